// Round 1
// baseline (6547.126 us; speedup 1.0000x reference)
//
#include <hip/hip_runtime.h>

#define NP 1600000
#define NNODES 50000
#define NEDGES 100000

// ---------------- f32 tiled GEMM: C = A @ W + bias, optional relu -----------
// A: [M,K] row-major, W: [K,N] row-major, C: [M,N]. K % 16 == 0, N % 128 == 0.
__global__ __launch_bounds__(256, 2) void gemm_f32(
    const float* __restrict__ A, const float* __restrict__ W,
    const float* __restrict__ bias, float* __restrict__ C,
    int M, int N, int K, int do_relu)
{
    __shared__ float As[16][128];   // transposed: As[k][row]
    __shared__ float Bs[16][128];   // Bs[k][col]

    const int tid = threadIdx.x;
    const int bn0 = blockIdx.x * 128;
    const int bm0 = blockIdx.y * 128;

    // wave-level 8x8 lane layout -> 2-way LDS bank aliasing (free)
    const int w = tid >> 6;
    const int l = tid & 63;
    const int col = (w & 1) * 64 + (l & 7) * 8;   // within BN
    const int row = (w >> 1) * 64 + (l >> 3) * 8; // within BM

    // global->LDS load assignment
    const int arow = tid >> 2;          // 0..63 (+64 for slot 1)
    const int acol = (tid & 3) * 4;     // k-offset 0,4,8,12
    const int bk   = tid >> 5;          // 0..7 (+8 for slot 1)
    const int bcol = (tid & 31) * 4;    // 0..124

    float acc[8][8];
#pragma unroll
    for (int i = 0; i < 8; ++i)
#pragma unroll
        for (int j = 0; j < 8; ++j) acc[i][j] = 0.f;

    const int nk = K >> 4;
    float4 aR[2], bR[2];

    // prologue: load tile 0 into regs
#pragma unroll
    for (int i = 0; i < 2; ++i) {
        int r = bm0 + arow + i * 64;
        if (r < M) aR[i] = *(const float4*)(A + (size_t)r * K + acol);
        else       aR[i] = make_float4(0.f, 0.f, 0.f, 0.f);
        int kk = bk + i * 8;
        bR[i] = *(const float4*)(W + (size_t)kk * N + bn0 + bcol);
    }

    for (int t = 0; t < nk; ++t) {
        __syncthreads();
#pragma unroll
        for (int i = 0; i < 2; ++i) {
            As[acol + 0][arow + i * 64] = aR[i].x;
            As[acol + 1][arow + i * 64] = aR[i].y;
            As[acol + 2][arow + i * 64] = aR[i].z;
            As[acol + 3][arow + i * 64] = aR[i].w;
            *(float4*)&Bs[bk + i * 8][bcol] = bR[i];
        }
        __syncthreads();
        if (t + 1 < nk) {
            const int kt = t + 1;
#pragma unroll
            for (int i = 0; i < 2; ++i) {
                int r = bm0 + arow + i * 64;
                if (r < M) aR[i] = *(const float4*)(A + (size_t)r * K + kt * 16 + acol);
                else       aR[i] = make_float4(0.f, 0.f, 0.f, 0.f);
                int kk = kt * 16 + bk + i * 8;
                bR[i] = *(const float4*)(W + (size_t)kk * N + bn0 + bcol);
            }
        }
#pragma unroll
        for (int k = 0; k < 16; ++k) {
            float4 a0 = *(const float4*)&As[k][row];
            float4 a1 = *(const float4*)&As[k][row + 4];
            float4 b0 = *(const float4*)&Bs[k][col];
            float4 b1 = *(const float4*)&Bs[k][col + 4];
            float av[8] = {a0.x, a0.y, a0.z, a0.w, a1.x, a1.y, a1.z, a1.w};
            float bv[8] = {b0.x, b0.y, b0.z, b0.w, b1.x, b1.y, b1.z, b1.w};
#pragma unroll
            for (int i = 0; i < 8; ++i)
#pragma unroll
                for (int j = 0; j < 8; ++j)
                    acc[i][j] = fmaf(av[i], bv[j], acc[i][j]);
        }
    }

    float bb[8];
#pragma unroll
    for (int j = 0; j < 8; ++j) bb[j] = bias[bn0 + col + j];

#pragma unroll
    for (int i = 0; i < 8; ++i) {
        int r = bm0 + row + i;
        if (r < M) {
            float o[8];
#pragma unroll
            for (int j = 0; j < 8; ++j) {
                float v = acc[i][j] + bb[j];
                if (do_relu) v = fmaxf(v, 0.f);
                o[j] = v;
            }
            float* cp = C + (size_t)r * N + bn0 + col;
            *(float4*)cp       = make_float4(o[0], o[1], o[2], o[3]);
            *(float4*)(cp + 4) = make_float4(o[4], o[5], o[6], o[7]);
        }
    }
}

// ---------------- histogram ----------------
__global__ void hist_kernel(const int* __restrict__ idx, int n, int* __restrict__ cnt)
{
    int i = blockIdx.x * blockDim.x + threadIdx.x;
    int stride = gridDim.x * blockDim.x;
    for (; i < n; i += stride) atomicAdd(&cnt[idx[i]], 1);
}

// ---------------- single-block exclusive scan (n <= 1024 * per) -------------
__global__ __launch_bounds__(1024) void exscan(const int* __restrict__ cnt,
                                               int* __restrict__ off, int n)
{
    __shared__ int sums[1024];
    const int t = threadIdx.x;
    const int per = (n + 1023) >> 10;
    const int b = t * per;
    const int e = min(b + per, n);
    int s = 0;
    for (int i = b; i < e; ++i) s += cnt[i];
    sums[t] = s;
    __syncthreads();
    for (int d = 1; d < 1024; d <<= 1) {
        int v = (t >= d) ? sums[t - d] : 0;
        __syncthreads();
        sums[t] += v;
        __syncthreads();
    }
    int run = (t > 0) ? sums[t - 1] : 0;
    for (int i = b; i < e; ++i) { off[i] = run; run += cnt[i]; }
    if (t == 1023) off[n] = run;
}

// ---------------- counting-sort scatter: e list grouped by vertex -----------
__global__ void scatter_kernel(const int* __restrict__ v_idx, const int* __restrict__ e_idx,
                               int n, const int* __restrict__ v_off,
                               int* __restrict__ cursor, int* __restrict__ e_by_v)
{
    int i = blockIdx.x * blockDim.x + threadIdx.x;
    int stride = gridDim.x * blockDim.x;
    for (; i < n; i += stride) {
        int v = v_idx[i];
        int pos = atomicAdd(&cursor[v], 1);
        e_by_v[v_off[v] + pos] = e_idx[i];
    }
}

// ---------------- segment mean via CSR gather ------------------------------
// dst[s, :] = mean over j in [off[s],off[s+1]) of src[idx[j], :]
template<int C>
__global__ void seg_mean(const float* __restrict__ src, const int* __restrict__ idx,
                         const int* __restrict__ off, float* __restrict__ dst, int do_relu)
{
    const int s = blockIdx.x;
    const int c = threadIdx.x;
    const int b = off[s], e = off[s + 1];
    float acc = 0.f;
    for (int j = b; j < e; ++j) acc += src[(size_t)idx[j] * C + c];
    acc /= fmaxf((float)(e - b), 1.f);
    if (do_relu) acc = fmaxf(acc, 0.f);
    dst[(size_t)s * C + c] = acc;
}

extern "C" void kernel_launch(void* const* d_in, const int* in_sizes, int n_in,
                              void* d_out, int out_size, void* d_ws, size_t ws_size,
                              hipStream_t stream)
{
    const float* m_emb = (const float*)d_in[0];
    const int*   v_pos = (const int*)d_in[1];
    const int*   e_pos = (const int*)d_in[2];
    const int*   v_neg = (const int*)d_in[3];
    const int*   e_neg = (const int*)d_in[4];
    const float* W0  = (const float*)d_in[5];
    const float* b0  = (const float*)d_in[6];
    const float* W1  = (const float*)d_in[7];
    const float* b1  = (const float*)d_in[8];
    const float* W2  = (const float*)d_in[9];
    const float* b2  = (const float*)d_in[10];
    const float* Wt1 = (const float*)d_in[11];
    const float* bt1 = (const float*)d_in[12];
    const float* Wt2 = (const float*)d_in[13];
    const float* bt2 = (const float*)d_in[14];
    float* out = (float*)d_out;

    // workspace carve (~341 MB)
    char* p = (char*)d_ws;
    auto carve = [&](size_t bytes) { char* r = p; p += (bytes + 255) & ~(size_t)255; return r; };
    float* bufA  = (float*)carve((size_t)NNODES * 512 * 4);  // h0, then feat
    float* bufB  = (float*)carve((size_t)NNODES * 512 * 4);  // h1, then Y1 [100000,256]
    float* Xt1   = (float*)carve((size_t)NNODES * 256 * 4);
    float* X1    = (float*)carve((size_t)NNODES * 256 * 4);
    float* Xt2   = (float*)carve((size_t)NNODES * 128 * 4);
    int*   e_off = (int*)carve((size_t)(NEDGES + 1) * 4);
    int*   v_off = (int*)carve((size_t)(NNODES + 1) * 4);
    int*   e_by_v= (int*)carve((size_t)NP * 4);
    int*   v_cnt = (int*)carve((size_t)NNODES * 4);
    int*   e_cnt = (int*)carve((size_t)NEDGES * 4);
    int*   cursor= (int*)carve((size_t)NNODES * 4);

    const int MB = (NNODES + 127) / 128; // 391

    // MLP: feat = (relu(relu(m_emb@W0+b0)@W1+b1))@W2+b2
    gemm_f32<<<dim3(4, MB), 256, 0, stream>>>(m_emb, W0, b0, bufA, NNODES, 512, 2816, 1);
    gemm_f32<<<dim3(4, MB), 256, 0, stream>>>(bufA, W1, b1, bufB, NNODES, 512, 512, 1);
    gemm_f32<<<dim3(4, MB), 256, 0, stream>>>(bufB, W2, b2, bufA, NNODES, 512, 512, 0);
    const float* feat = bufA;

    auto do_sign = [&](const int* v_idx, const int* e_idx, float* outX, float* outY) {
        // build CSR (edge side relies on sorted e_idx; vertex side via counting sort)
        hipMemsetAsync(v_cnt, 0, (size_t)NNODES * 4, stream);
        hipMemsetAsync(e_cnt, 0, (size_t)NEDGES * 4, stream);
        hipMemsetAsync(cursor, 0, (size_t)NNODES * 4, stream);
        hist_kernel<<<2048, 256, 0, stream>>>(v_idx, NP, v_cnt);
        hist_kernel<<<2048, 256, 0, stream>>>(e_idx, NP, e_cnt);
        exscan<<<1, 1024, 0, stream>>>(e_cnt, e_off, NEDGES);
        exscan<<<1, 1024, 0, stream>>>(v_cnt, v_off, NNODES);
        scatter_kernel<<<2048, 256, 0, stream>>>(v_idx, e_idx, NP, v_off, cursor, e_by_v);

        // layer 1: 512 -> 256, relu at the end
        gemm_f32<<<dim3(2, MB), 256, 0, stream>>>(feat, Wt1, bt1, Xt1, NNODES, 256, 512, 0);
        seg_mean<256><<<NEDGES, 256, 0, stream>>>(Xt1, v_idx, e_off, bufB, 0);   // Y1
        seg_mean<256><<<NNODES, 256, 0, stream>>>(bufB, e_by_v, v_off, X1, 1);   // relu(X)

        // layer 2: 256 -> 128, no relu; Y and X go straight to d_out
        gemm_f32<<<dim3(1, MB), 256, 0, stream>>>(X1, Wt2, bt2, Xt2, NNODES, 128, 256, 0);
        seg_mean<128><<<NEDGES, 128, 0, stream>>>(Xt2, v_idx, e_off, outY, 0);
        seg_mean<128><<<NNODES, 128, 0, stream>>>(outY, e_by_v, v_off, outX, 0);
    };

    // out layout: X1 [50000*128], X2 [50000*128], Y_pos [100000*128], Y_neg [100000*128]
    do_sign(v_pos, e_pos, out,            out + 12800000);
    do_sign(v_neg, e_neg, out + 6400000,  out + 25600000);
}

// Round 2
// 4135.052 us; speedup vs baseline: 1.5833x; 1.5833x over previous
//
#include <hip/hip_runtime.h>

#define NP 1600000
#define NNODES 50000
#define NEDGES 100000

typedef short bf16x8 __attribute__((ext_vector_type(8)));
typedef short short4b __attribute__((ext_vector_type(4)));
typedef float f32x4 __attribute__((ext_vector_type(4)));
typedef unsigned short ushort_t;

static __device__ __forceinline__ ushort_t f2bf(float f) {
    union { float f; unsigned int u; } v; v.f = f;
    unsigned int r = (v.u + 0x7fffu + ((v.u >> 16) & 1u)) >> 16;
    return (ushort_t)r;
}
static __device__ __forceinline__ float bf2f(ushort_t h) {
    union { float f; unsigned int u; } v; v.u = ((unsigned int)h) << 16;
    return v.f;
}

static __device__ __forceinline__ void gload_lds16(const void* g, void* lds) {
    __builtin_amdgcn_global_load_lds(
        (const __attribute__((address_space(1))) unsigned int*)g,
        (__attribute__((address_space(3))) unsigned int*)lds, 16, 0, 0);
}

// ---------------- bf16x3 split MFMA GEMM ------------------------------------
// C = A @ B + bias.  A [M,K] (f32 or bf16 hi/lo), B given transposed [N,K] bf16 hi/lo.
// BM=128, BN=128, BK=32. 4 waves, each computes 64x64. 16x16x32 MFMA.
// LDS layout [kg][row][8]: element (row,k) at [(k>>3)][row][k&7] -> conflict-free
// ds_read_b128 frags AND linear global_load_lds staging (dest = base + lane*16).
template<bool AF32, bool DORELU, bool WF32, bool WSPLIT>
__global__ __launch_bounds__(256, 2) void gemm_bf3(
    const float* __restrict__ Af,
    const ushort_t* __restrict__ Ah, const ushort_t* __restrict__ Al,
    const ushort_t* __restrict__ Bth, const ushort_t* __restrict__ Btl,
    const float* __restrict__ bias,
    float* __restrict__ Cf, ushort_t* __restrict__ Ch, ushort_t* __restrict__ Cl,
    int M, int N, int K)
{
    __shared__ ushort_t AsH[4][128][8];
    __shared__ ushort_t AsL[4][128][8];
    __shared__ ushort_t BsH[4][128][8];
    __shared__ ushort_t BsL[4][128][8];

    const int tid = threadIdx.x;
    const int wid = tid >> 6;
    const int lane = tid & 63;
    const int bn0 = blockIdx.x * 128;
    const int bm0 = blockIdx.y * 128;
    const int wrow0 = (wid >> 1) * 64;
    const int wcol0 = (wid & 1) * 64;

    f32x4 acc[4][4];
#pragma unroll
    for (int i = 0; i < 4; ++i)
#pragma unroll
        for (int j = 0; j < 4; ++j) acc[i][j] = (f32x4)0.f;

    const int nk = K >> 5;
    const int kgl = lane >> 4;      // frag k-group
    const int r16 = lane & 15;

    for (int kt = 0; kt < nk; ++kt) {
        __syncthreads();
        // ---- stage B (always bf16, transposed source [N,K]) ----
#pragma unroll
        for (int h = 0; h < 2; ++h) {
            int c = bn0 + h * 64 + lane;
            const ushort_t* gbh = Bth + (size_t)c * K + kt * 32 + wid * 8;
            const ushort_t* gbl = Btl + (size_t)c * K + kt * 32 + wid * 8;
            gload_lds16(gbh, &BsH[wid][h * 64][0]);
            gload_lds16(gbl, &BsL[wid][h * 64][0]);
        }
        // ---- stage A ----
        if constexpr (AF32) {
#pragma unroll
            for (int cch = 0; cch < 4; ++cch) {
                int idx = cch * 256 + tid;      // 0..1023
                int row = idx >> 3;             // 0..127
                int kq = idx & 7;               // quad of 4 f32
                int r = bm0 + row; if (r > M - 1) r = M - 1;
                float4 v = *(const float4*)(Af + (size_t)r * K + kt * 32 + kq * 4);
                short4b hi, lo;
                ushort_t h0 = f2bf(v.x), h1 = f2bf(v.y), h2 = f2bf(v.z), h3 = f2bf(v.w);
                hi[0] = (short)h0; hi[1] = (short)h1; hi[2] = (short)h2; hi[3] = (short)h3;
                lo[0] = (short)f2bf(v.x - bf2f(h0));
                lo[1] = (short)f2bf(v.y - bf2f(h1));
                lo[2] = (short)f2bf(v.z - bf2f(h2));
                lo[3] = (short)f2bf(v.w - bf2f(h3));
                int kg = kq >> 1, j0 = (kq & 1) * 4;
                *(short4b*)&AsH[kg][row][j0] = hi;
                *(short4b*)&AsL[kg][row][j0] = lo;
            }
        } else {
#pragma unroll
            for (int h = 0; h < 2; ++h) {
                int r = bm0 + h * 64 + lane; if (r > M - 1) r = M - 1;
                const ushort_t* gah = Ah + (size_t)r * K + kt * 32 + wid * 8;
                const ushort_t* gal = Al + (size_t)r * K + kt * 32 + wid * 8;
                gload_lds16(gah, &AsH[wid][h * 64][0]);
                gload_lds16(gal, &AsL[wid][h * 64][0]);
            }
        }
        __syncthreads();

        // ---- fragments ----
        bf16x8 ah[4], al[4], bh[4], bl[4];
#pragma unroll
        for (int mi = 0; mi < 4; ++mi) {
            ah[mi] = *(const bf16x8*)&AsH[kgl][wrow0 + mi * 16 + r16][0];
            al[mi] = *(const bf16x8*)&AsL[kgl][wrow0 + mi * 16 + r16][0];
        }
#pragma unroll
        for (int ni = 0; ni < 4; ++ni) {
            bh[ni] = *(const bf16x8*)&BsH[kgl][wcol0 + ni * 16 + r16][0];
            bl[ni] = *(const bf16x8*)&BsL[kgl][wcol0 + ni * 16 + r16][0];
        }
#pragma unroll
        for (int mi = 0; mi < 4; ++mi)
#pragma unroll
            for (int ni = 0; ni < 4; ++ni) {
                acc[mi][ni] = __builtin_amdgcn_mfma_f32_16x16x32_bf16(ah[mi], bh[ni], acc[mi][ni], 0, 0, 0);
                acc[mi][ni] = __builtin_amdgcn_mfma_f32_16x16x32_bf16(ah[mi], bl[ni], acc[mi][ni], 0, 0, 0);
                acc[mi][ni] = __builtin_amdgcn_mfma_f32_16x16x32_bf16(al[mi], bh[ni], acc[mi][ni], 0, 0, 0);
            }
    }

    // ---- epilogue: C/D layout col=lane&15 (N), row=(lane>>4)*4+reg (M) ----
    const int rg4 = (lane >> 4) * 4;
#pragma unroll
    for (int ni = 0; ni < 4; ++ni) {
        int gcol = bn0 + wcol0 + ni * 16 + r16;
        float bb = bias[gcol];
#pragma unroll
        for (int mi = 0; mi < 4; ++mi)
#pragma unroll
            for (int rg = 0; rg < 4; ++rg) {
                int grow = bm0 + wrow0 + mi * 16 + rg4 + rg;
                if (grow < M) {
                    float v = acc[mi][ni][rg] + bb;
                    if constexpr (DORELU) v = fmaxf(v, 0.f);
                    if constexpr (WF32) Cf[(size_t)grow * N + gcol] = v;
                    if constexpr (WSPLIT) {
                        ushort_t h = f2bf(v);
                        Ch[(size_t)grow * N + gcol] = h;
                        Cl[(size_t)grow * N + gcol] = f2bf(v - bf2f(h));
                    }
                }
            }
    }
}

// ---------------- weight transpose + split: W[K,N] f32 -> Bt hi/lo [N,K] ----
__global__ __launch_bounds__(256) void transp_split(
    const float* __restrict__ W, ushort_t* __restrict__ BtH, ushort_t* __restrict__ BtL,
    int K, int N)
{
    __shared__ float T[32][33];
    const int n0 = blockIdx.x * 32, k0 = blockIdx.y * 32;
    const int c = threadIdx.x & 31, r8 = threadIdx.x >> 5;
#pragma unroll
    for (int i = 0; i < 4; ++i) {
        int kr = r8 + i * 8;
        T[kr][c] = W[(size_t)(k0 + kr) * N + n0 + c];
    }
    __syncthreads();
#pragma unroll
    for (int i = 0; i < 4; ++i) {
        int nr = r8 + i * 8;
        float v = T[c][nr];
        ushort_t h = f2bf(v);
        BtH[(size_t)(n0 + nr) * K + k0 + c] = h;
        BtL[(size_t)(n0 + nr) * K + k0 + c] = f2bf(v - bf2f(h));
    }
}

// ---------------- histogram ----------------
__global__ void hist_kernel(const int* __restrict__ idx, int n, int* __restrict__ cnt)
{
    int i = blockIdx.x * blockDim.x + threadIdx.x;
    int stride = gridDim.x * blockDim.x;
    for (; i < n; i += stride) atomicAdd(&cnt[idx[i]], 1);
}

// ---------------- single-block exclusive scan -------------------------------
__global__ __launch_bounds__(1024) void exscan(const int* __restrict__ cnt,
                                               int* __restrict__ off, int n)
{
    __shared__ int sums[1024];
    const int t = threadIdx.x;
    const int per = (n + 1023) >> 10;
    const int b = t * per;
    const int e = min(b + per, n);
    int s = 0;
    for (int i = b; i < e; ++i) s += cnt[i];
    sums[t] = s;
    __syncthreads();
    for (int d = 1; d < 1024; d <<= 1) {
        int v = (t >= d) ? sums[t - d] : 0;
        __syncthreads();
        sums[t] += v;
        __syncthreads();
    }
    int run = (t > 0) ? sums[t - 1] : 0;
    for (int i = b; i < e; ++i) { off[i] = run; run += cnt[i]; }
    if (t == 1023) off[n] = run;
}

// ---------------- counting-sort scatter -------------------------------------
__global__ void scatter_kernel(const int* __restrict__ v_idx, const int* __restrict__ e_idx,
                               int n, const int* __restrict__ v_off,
                               int* __restrict__ cursor, int* __restrict__ e_by_v)
{
    int i = blockIdx.x * blockDim.x + threadIdx.x;
    int stride = gridDim.x * blockDim.x;
    for (; i < n; i += stride) {
        int v = v_idx[i];
        int pos = atomicAdd(&cursor[v], 1);
        e_by_v[v_off[v] + pos] = e_idx[i];
    }
}

// ---------------- segment mean via CSR gather -------------------------------
template<int C, bool DORELU, bool WF32, bool WSPLIT>
__global__ void seg_mean(const float* __restrict__ src, const int* __restrict__ idx,
                         const int* __restrict__ off, float* __restrict__ dst,
                         ushort_t* __restrict__ dH, ushort_t* __restrict__ dL)
{
    const int s = blockIdx.x;
    const int c = threadIdx.x;
    const int b = off[s], e = off[s + 1];
    float acc = 0.f;
    for (int j = b; j < e; ++j) acc += src[(size_t)idx[j] * C + c];
    acc /= fmaxf((float)(e - b), 1.f);
    if constexpr (DORELU) acc = fmaxf(acc, 0.f);
    if constexpr (WF32) dst[(size_t)s * C + c] = acc;
    if constexpr (WSPLIT) {
        ushort_t h = f2bf(acc);
        dH[(size_t)s * C + c] = h;
        dL[(size_t)s * C + c] = f2bf(acc - bf2f(h));
    }
}

extern "C" void kernel_launch(void* const* d_in, const int* in_sizes, int n_in,
                              void* d_out, int out_size, void* d_ws, size_t ws_size,
                              hipStream_t stream)
{
    const float* m_emb = (const float*)d_in[0];
    const int*   v_pos = (const int*)d_in[1];
    const int*   e_pos = (const int*)d_in[2];
    const int*   v_neg = (const int*)d_in[3];
    const int*   e_neg = (const int*)d_in[4];
    const float* W0  = (const float*)d_in[5];
    const float* b0  = (const float*)d_in[6];
    const float* W1  = (const float*)d_in[7];
    const float* b1  = (const float*)d_in[8];
    const float* W2  = (const float*)d_in[9];
    const float* b2  = (const float*)d_in[10];
    const float* Wt1 = (const float*)d_in[11];
    const float* bt1 = (const float*)d_in[12];
    const float* Wt2 = (const float*)d_in[13];
    const float* bt2 = (const float*)d_in[14];
    float* out = (float*)d_out;

    // ---- workspace carve (~355 MB) ----
    char* p = (char*)d_ws;
    auto carve = [&](size_t bytes) { char* r = p; p += (bytes + 255) & ~(size_t)255; return r; };
    const size_t NA = (size_t)NNODES * 512;          // 25.6M elems
    ushort_t* regA_H = (ushort_t*)carve(NA * 2);     // h0 hi, later feat hi
    ushort_t* regA_L = (ushort_t*)carve(NA * 2);     // h0 lo, later feat lo
    ushort_t* regB_H = (ushort_t*)carve(NA * 2);     // h1 hi
    ushort_t* regB_L = (ushort_t*)carve(NA * 2);     // h1 lo
    // after G2: reuse regB region: Xt1 f32 (51.2MB) + X1 hi/lo (25.6+25.6MB)
    float*    Xt1  = (float*)regB_H;                              // [50000,256] f32
    ushort_t* X1H  = (ushort_t*)((char*)regB_H + NA * 2);         // [50000,256] bf16
    ushort_t* X1L  = (ushort_t*)((char*)regB_H + NA * 3);
    float* Y1   = (float*)carve((size_t)NEDGES * 256 * 4);        // 102.4 MB
    float* Xt2  = (float*)carve((size_t)NNODES * 128 * 4);        // 25.6 MB
    // transposed/split weights
    ushort_t* W0tH  = (ushort_t*)carve((size_t)512 * 2816 * 2);
    ushort_t* W0tL  = (ushort_t*)carve((size_t)512 * 2816 * 2);
    ushort_t* W1tH  = (ushort_t*)carve((size_t)512 * 512 * 2);
    ushort_t* W1tL  = (ushort_t*)carve((size_t)512 * 512 * 2);
    ushort_t* W2tH  = (ushort_t*)carve((size_t)512 * 512 * 2);
    ushort_t* W2tL  = (ushort_t*)carve((size_t)512 * 512 * 2);
    ushort_t* Wt1tH = (ushort_t*)carve((size_t)256 * 512 * 2);
    ushort_t* Wt1tL = (ushort_t*)carve((size_t)256 * 512 * 2);
    ushort_t* Wt2tH = (ushort_t*)carve((size_t)128 * 256 * 2);
    ushort_t* Wt2tL = (ushort_t*)carve((size_t)128 * 256 * 2);
    int* e_off  = (int*)carve((size_t)(NEDGES + 1) * 4);
    int* v_off  = (int*)carve((size_t)(NNODES + 1) * 4);
    int* e_by_v = (int*)carve((size_t)NP * 4);
    int* v_cnt  = (int*)carve((size_t)NNODES * 4);
    int* e_cnt  = (int*)carve((size_t)NEDGES * 4);
    int* cursor = (int*)carve((size_t)NNODES * 4);

    const int MB = (NNODES + 127) / 128; // 391

    // ---- weight prep ----
    transp_split<<<dim3(16, 88), 256, 0, stream>>>(W0, W0tH, W0tL, 2816, 512);
    transp_split<<<dim3(16, 16), 256, 0, stream>>>(W1, W1tH, W1tL, 512, 512);
    transp_split<<<dim3(16, 16), 256, 0, stream>>>(W2, W2tH, W2tL, 512, 512);
    transp_split<<<dim3(8, 16),  256, 0, stream>>>(Wt1, Wt1tH, Wt1tL, 512, 256);
    transp_split<<<dim3(4, 8),   256, 0, stream>>>(Wt2, Wt2tH, Wt2tL, 256, 128);

    // ---- MLP: h0 = relu(m_emb@W0+b0); h1 = relu(h0@W1+b1); feat = h1@W2+b2 ----
    gemm_bf3<true, true, false, true><<<dim3(4, MB), 256, 0, stream>>>(
        m_emb, nullptr, nullptr, W0tH, W0tL, b0, nullptr, regA_H, regA_L, NNODES, 512, 2816);
    gemm_bf3<false, true, false, true><<<dim3(4, MB), 256, 0, stream>>>(
        nullptr, regA_H, regA_L, W1tH, W1tL, b1, nullptr, regB_H, regB_L, NNODES, 512, 512);
    gemm_bf3<false, false, false, true><<<dim3(4, MB), 256, 0, stream>>>(
        nullptr, regB_H, regB_L, W2tH, W2tL, b2, nullptr, regA_H, regA_L, NNODES, 512, 512);
    const ushort_t* featH = regA_H;
    const ushort_t* featL = regA_L;

    auto do_sign = [&](const int* v_idx, const int* e_idx, float* outX, float* outY) {
        hipMemsetAsync(v_cnt, 0, (size_t)NNODES * 4, stream);
        hipMemsetAsync(e_cnt, 0, (size_t)NEDGES * 4, stream);
        hipMemsetAsync(cursor, 0, (size_t)NNODES * 4, stream);
        hist_kernel<<<2048, 256, 0, stream>>>(v_idx, NP, v_cnt);
        hist_kernel<<<2048, 256, 0, stream>>>(e_idx, NP, e_cnt);
        exscan<<<1, 1024, 0, stream>>>(e_cnt, e_off, NEDGES);
        exscan<<<1, 1024, 0, stream>>>(v_cnt, v_off, NNODES);
        scatter_kernel<<<2048, 256, 0, stream>>>(v_idx, e_idx, NP, v_off, cursor, e_by_v);

        // layer 1: Xt1 = feat@Wt1+bt1 ; Y1 = v2e-mean(Xt1); X1 = relu(e2v-mean(Y1))
        gemm_bf3<false, false, true, false><<<dim3(2, MB), 256, 0, stream>>>(
            nullptr, featH, featL, Wt1tH, Wt1tL, bt1, Xt1, nullptr, nullptr, NNODES, 256, 512);
        seg_mean<256, false, true, false><<<NEDGES, 256, 0, stream>>>(Xt1, v_idx, e_off, Y1, nullptr, nullptr);
        seg_mean<256, true, false, true><<<NNODES, 256, 0, stream>>>(Y1, e_by_v, v_off, nullptr, X1H, X1L);

        // layer 2: Xt2 = X1@Wt2+bt2 ; outY = v2e-mean(Xt2); outX = e2v-mean(outY)
        gemm_bf3<false, false, true, false><<<dim3(1, MB), 256, 0, stream>>>(
            nullptr, X1H, X1L, Wt2tH, Wt2tL, bt2, Xt2, nullptr, nullptr, NNODES, 128, 256);
        seg_mean<128, false, true, false><<<NEDGES, 128, 0, stream>>>(Xt2, v_idx, e_off, outY, nullptr, nullptr);
        seg_mean<128, false, true, false><<<NNODES, 128, 0, stream>>>(outY, e_by_v, v_off, outX, nullptr, nullptr);
    };

    // out layout: X1 [50000*128], X2 [50000*128], Y_pos [100000*128], Y_neg [100000*128]
    do_sign(v_pos, e_pos, out,           out + 12800000);
    do_sign(v_neg, e_neg, out + 6400000, out + 25600000);
}

// Round 3
// 2919.802 us; speedup vs baseline: 2.2423x; 1.4162x over previous
//
#include <hip/hip_runtime.h>

#define NP 1600000
#define NNODES 50000
#define NEDGES 100000

typedef short bf16x8 __attribute__((ext_vector_type(8)));
typedef short short4b __attribute__((ext_vector_type(4)));
typedef float f32x4 __attribute__((ext_vector_type(4)));
typedef unsigned short ushort_t;

template<int N> struct VecT;
template<> struct VecT<2> { typedef float type __attribute__((ext_vector_type(2))); };
template<> struct VecT<4> { typedef float type __attribute__((ext_vector_type(4))); };

static __device__ __forceinline__ ushort_t f2bf(float f) {
    union { float f; unsigned int u; } v; v.f = f;
    unsigned int r = (v.u + 0x7fffu + ((v.u >> 16) & 1u)) >> 16;
    return (ushort_t)r;
}
static __device__ __forceinline__ float bf2f(ushort_t h) {
    union { float f; unsigned int u; } v; v.u = ((unsigned int)h) << 16;
    return v.f;
}

static __device__ __forceinline__ void gload_lds16(const void* g, void* lds) {
    __builtin_amdgcn_global_load_lds(
        (const __attribute__((address_space(1))) unsigned int*)g,
        (__attribute__((address_space(3))) unsigned int*)lds, 16, 0, 0);
}

// ---------------- bf16x3 split MFMA GEMM ------------------------------------
// C = A @ B + bias.  A [M,K] (f32 or bf16 hi/lo), B transposed [N,K] bf16 hi/lo.
// BM=BN=128, BK=32, 4 waves x (64x64), 16x16x32 MFMA, split-3 (AhBh+AhBl+AlBh).
// AF32 path: register-prefetch of next K-tile issued during MFMA phase (T14).
template<bool AF32, bool DORELU, bool WF32, bool WSPLIT>
__global__ __launch_bounds__(256, 2) void gemm_bf3(
    const float* __restrict__ Af,
    const ushort_t* __restrict__ Ah, const ushort_t* __restrict__ Al,
    const ushort_t* __restrict__ Bth, const ushort_t* __restrict__ Btl,
    const float* __restrict__ bias,
    float* __restrict__ Cf, ushort_t* __restrict__ Ch, ushort_t* __restrict__ Cl,
    int M, int N, int K)
{
    __shared__ ushort_t AsH[4][128][8];
    __shared__ ushort_t AsL[4][128][8];
    __shared__ ushort_t BsH[4][128][8];
    __shared__ ushort_t BsL[4][128][8];

    const int tid = threadIdx.x;
    const int wid = tid >> 6;
    const int lane = tid & 63;
    const int bn0 = blockIdx.x * 128;
    const int bm0 = blockIdx.y * 128;
    const int wrow0 = (wid >> 1) * 64;
    const int wcol0 = (wid & 1) * 64;

    f32x4 acc[4][4];
#pragma unroll
    for (int i = 0; i < 4; ++i)
#pragma unroll
        for (int j = 0; j < 4; ++j) acc[i][j] = (f32x4)0.f;

    const int nk = K >> 5;
    const int kgl = lane >> 4;
    const int r16 = lane & 15;

    // AF32 A-staging geometry (hoisted)
    const int a_kq   = tid & 7;           // which float4 quad in the 32-k tile
    const int a_row0 = tid >> 3;          // row base; rows = a_row0 + cch*32
    const float* aBase[4];
    float4 aPre[4];
    if constexpr (AF32) {
#pragma unroll
        for (int cch = 0; cch < 4; ++cch) {
            int row = cch * 32 + a_row0;
            int r = bm0 + row; if (r > M - 1) r = M - 1;
            aBase[cch] = Af + (size_t)r * K + a_kq * 4;
            aPre[cch] = *(const float4*)(aBase[cch]);   // tile 0
        }
    }

    for (int kt = 0; kt < nk; ++kt) {
        __syncthreads();
        // ---- stage B (async) ----
#pragma unroll
        for (int h = 0; h < 2; ++h) {
            int c = bn0 + h * 64 + lane;
            const ushort_t* gbh = Bth + (size_t)c * K + kt * 32 + wid * 8;
            const ushort_t* gbl = Btl + (size_t)c * K + kt * 32 + wid * 8;
            gload_lds16(gbh, &BsH[wid][h * 64][0]);
            gload_lds16(gbl, &BsL[wid][h * 64][0]);
        }
        // ---- stage A ----
        if constexpr (AF32) {
            // convert the prefetched registers, write to LDS
#pragma unroll
            for (int cch = 0; cch < 4; ++cch) {
                int row = cch * 32 + a_row0;
                float4 v = aPre[cch];
                short4b hi, lo;
                ushort_t h0 = f2bf(v.x), h1 = f2bf(v.y), h2 = f2bf(v.z), h3 = f2bf(v.w);
                hi[0] = (short)h0; hi[1] = (short)h1; hi[2] = (short)h2; hi[3] = (short)h3;
                lo[0] = (short)f2bf(v.x - bf2f(h0));
                lo[1] = (short)f2bf(v.y - bf2f(h1));
                lo[2] = (short)f2bf(v.z - bf2f(h2));
                lo[3] = (short)f2bf(v.w - bf2f(h3));
                int kg = a_kq >> 1, j0 = (a_kq & 1) * 4;
                *(short4b*)&AsH[kg][row][j0] = hi;
                *(short4b*)&AsL[kg][row][j0] = lo;
            }
        } else {
#pragma unroll
            for (int h = 0; h < 2; ++h) {
                int r = bm0 + h * 64 + lane; if (r > M - 1) r = M - 1;
                const ushort_t* gah = Ah + (size_t)r * K + kt * 32 + wid * 8;
                const ushort_t* gal = Al + (size_t)r * K + kt * 32 + wid * 8;
                gload_lds16(gah, &AsH[wid][h * 64][0]);
                gload_lds16(gal, &AsL[wid][h * 64][0]);
            }
        }
        __syncthreads();

        // ---- issue next A f32 loads NOW; latency hides under MFMA ----
        if constexpr (AF32) {
            if (kt + 1 < nk) {
#pragma unroll
                for (int cch = 0; cch < 4; ++cch)
                    aPre[cch] = *(const float4*)(aBase[cch] + (kt + 1) * 32);
            }
        }

        // ---- fragments ----
        bf16x8 ah[4], al[4], bh[4], bl[4];
#pragma unroll
        for (int mi = 0; mi < 4; ++mi) {
            ah[mi] = *(const bf16x8*)&AsH[kgl][wrow0 + mi * 16 + r16][0];
            al[mi] = *(const bf16x8*)&AsL[kgl][wrow0 + mi * 16 + r16][0];
        }
#pragma unroll
        for (int ni = 0; ni < 4; ++ni) {
            bh[ni] = *(const bf16x8*)&BsH[kgl][wcol0 + ni * 16 + r16][0];
            bl[ni] = *(const bf16x8*)&BsL[kgl][wcol0 + ni * 16 + r16][0];
        }
#pragma unroll
        for (int mi = 0; mi < 4; ++mi)
#pragma unroll
            for (int ni = 0; ni < 4; ++ni) {
                acc[mi][ni] = __builtin_amdgcn_mfma_f32_16x16x32_bf16(ah[mi], bh[ni], acc[mi][ni], 0, 0, 0);
                acc[mi][ni] = __builtin_amdgcn_mfma_f32_16x16x32_bf16(ah[mi], bl[ni], acc[mi][ni], 0, 0, 0);
                acc[mi][ni] = __builtin_amdgcn_mfma_f32_16x16x32_bf16(al[mi], bh[ni], acc[mi][ni], 0, 0, 0);
            }
    }

    // ---- epilogue: C/D layout col=lane&15 (N), row=(lane>>4)*4+reg (M) ----
    const int rg4 = (lane >> 4) * 4;
#pragma unroll
    for (int ni = 0; ni < 4; ++ni) {
        int gcol = bn0 + wcol0 + ni * 16 + r16;
        float bb = bias[gcol];
#pragma unroll
        for (int mi = 0; mi < 4; ++mi)
#pragma unroll
            for (int rg = 0; rg < 4; ++rg) {
                int grow = bm0 + wrow0 + mi * 16 + rg4 + rg;
                if (grow < M) {
                    float v = acc[mi][ni][rg] + bb;
                    if constexpr (DORELU) v = fmaxf(v, 0.f);
                    if constexpr (WF32) Cf[(size_t)grow * N + gcol] = v;
                    if constexpr (WSPLIT) {
                        ushort_t h = f2bf(v);
                        Ch[(size_t)grow * N + gcol] = h;
                        Cl[(size_t)grow * N + gcol] = f2bf(v - bf2f(h));
                    }
                }
            }
    }
}

// ---------------- weight transpose + split: W[K,N] f32 -> Bt hi/lo [N,K] ----
__global__ __launch_bounds__(256) void transp_split(
    const float* __restrict__ W, ushort_t* __restrict__ BtH, ushort_t* __restrict__ BtL,
    int K, int N)
{
    __shared__ float T[32][33];
    const int n0 = blockIdx.x * 32, k0 = blockIdx.y * 32;
    const int c = threadIdx.x & 31, r8 = threadIdx.x >> 5;
#pragma unroll
    for (int i = 0; i < 4; ++i) {
        int kr = r8 + i * 8;
        T[kr][c] = W[(size_t)(k0 + kr) * N + n0 + c];
    }
    __syncthreads();
#pragma unroll
    for (int i = 0; i < 4; ++i) {
        int nr = r8 + i * 8;
        float v = T[c][nr];
        ushort_t h = f2bf(v);
        BtH[(size_t)(n0 + nr) * K + k0 + c] = h;
        BtL[(size_t)(n0 + nr) * K + k0 + c] = f2bf(v - bf2f(h));
    }
}

// ---------------- edge CSR offsets from SORTED e_idx -------------------------
__global__ void edge_off_sorted(const int* __restrict__ e_idx, int n,
                                int* __restrict__ off, int nseg)
{
    int i = blockIdx.x * blockDim.x + threadIdx.x;
    int stride = gridDim.x * blockDim.x;
    for (; i < n; i += stride) {
        int cur = e_idx[i];
        int prev = (i > 0) ? e_idx[i - 1] : -1;
        for (int e = prev + 1; e <= cur; ++e) off[e] = i;
        if (i == n - 1)
            for (int e = cur + 1; e <= nseg; ++e) off[e] = n;
    }
}

// ---------------- histogram ----------------
__global__ void hist_kernel(const int* __restrict__ idx, int n, int* __restrict__ cnt)
{
    int i = blockIdx.x * blockDim.x + threadIdx.x;
    int stride = gridDim.x * blockDim.x;
    for (; i < n; i += stride) atomicAdd(&cnt[idx[i]], 1);
}

// ---------------- single-block exclusive scan -------------------------------
__global__ __launch_bounds__(1024) void exscan(const int* __restrict__ cnt,
                                               int* __restrict__ off, int n)
{
    __shared__ int sums[1024];
    const int t = threadIdx.x;
    const int per = (n + 1023) >> 10;
    const int b = t * per;
    const int e = min(b + per, n);
    int s = 0;
    for (int i = b; i < e; ++i) s += cnt[i];
    sums[t] = s;
    __syncthreads();
    for (int d = 1; d < 1024; d <<= 1) {
        int v = (t >= d) ? sums[t - d] : 0;
        __syncthreads();
        sums[t] += v;
        __syncthreads();
    }
    int run = (t > 0) ? sums[t - 1] : 0;
    for (int i = b; i < e; ++i) { off[i] = run; run += cnt[i]; }
    if (t == 1023) off[n] = run;
}

// ---------------- counting-sort scatter (v_cnt doubles as countdown cursor) -
__global__ void scatter_kernel(const int* __restrict__ v_idx, const int* __restrict__ e_idx,
                               int n, const int* __restrict__ v_off,
                               int* __restrict__ v_cnt, int* __restrict__ e_by_v)
{
    int i = blockIdx.x * blockDim.x + threadIdx.x;
    int stride = gridDim.x * blockDim.x;
    for (; i < n; i += stride) {
        int v = v_idx[i];
        int pos = atomicSub(&v_cnt[v], 1) - 1;
        e_by_v[v_off[v] + pos] = e_idx[i];
    }
}

// ---------------- segment mean: one wave per segment, VEC floats/lane -------
template<int C, bool DORELU, bool WF32, bool WSPLIT>
__global__ __launch_bounds__(256) void seg_mean(
    const float* __restrict__ src, const int* __restrict__ idx,
    const int* __restrict__ off, float* __restrict__ dst,
    ushort_t* __restrict__ dH, ushort_t* __restrict__ dL, int nseg)
{
    constexpr int VEC = C / 64;
    typedef typename VecT<VEC>::type fvec;
    const int wave = threadIdx.x >> 6, lane = threadIdx.x & 63;
    const int s = blockIdx.x * 4 + wave;
    if (s >= nseg) return;
    const int b = off[s], e = off[s + 1];
    const int cbase = lane * VEC;

    fvec a0 = (fvec)0.f, a1 = (fvec)0.f, a2 = (fvec)0.f, a3 = (fvec)0.f;
    int j = b;
    const int e4 = b + ((e - b) & ~3);
    for (; j < e4; j += 4) {
        int i0 = idx[j], i1 = idx[j + 1], i2 = idx[j + 2], i3 = idx[j + 3];
        fvec v0 = *(const fvec*)(src + (size_t)i0 * C + cbase);
        fvec v1 = *(const fvec*)(src + (size_t)i1 * C + cbase);
        fvec v2 = *(const fvec*)(src + (size_t)i2 * C + cbase);
        fvec v3 = *(const fvec*)(src + (size_t)i3 * C + cbase);
        a0 += v0; a1 += v1; a2 += v2; a3 += v3;
    }
    for (; j < e; ++j)
        a0 += *(const fvec*)(src + (size_t)idx[j] * C + cbase);
    fvec acc = (a0 + a1) + (a2 + a3);

    const float inv = 1.f / fmaxf((float)(e - b), 1.f);
#pragma unroll
    for (int k = 0; k < VEC; ++k) {
        float v = acc[k] * inv;
        if constexpr (DORELU) v = fmaxf(v, 0.f);
        if constexpr (WF32) dst[(size_t)s * C + cbase + k] = v;
        if constexpr (WSPLIT) {
            ushort_t h = f2bf(v);
            dH[(size_t)s * C + cbase + k] = h;
            dL[(size_t)s * C + cbase + k] = f2bf(v - bf2f(h));
        }
    }
}

extern "C" void kernel_launch(void* const* d_in, const int* in_sizes, int n_in,
                              void* d_out, int out_size, void* d_ws, size_t ws_size,
                              hipStream_t stream)
{
    const float* m_emb = (const float*)d_in[0];
    const int*   v_pos = (const int*)d_in[1];
    const int*   e_pos = (const int*)d_in[2];
    const int*   v_neg = (const int*)d_in[3];
    const int*   e_neg = (const int*)d_in[4];
    const float* W0  = (const float*)d_in[5];
    const float* b0  = (const float*)d_in[6];
    const float* W1  = (const float*)d_in[7];
    const float* b1  = (const float*)d_in[8];
    const float* W2  = (const float*)d_in[9];
    const float* b2  = (const float*)d_in[10];
    const float* Wt1 = (const float*)d_in[11];
    const float* bt1 = (const float*)d_in[12];
    const float* Wt2 = (const float*)d_in[13];
    const float* bt2 = (const float*)d_in[14];
    float* out = (float*)d_out;

    // ---- workspace carve (~272 MB) ----
    char* p = (char*)d_ws;
    auto carve = [&](size_t bytes) { char* r = p; p += (bytes + 255) & ~(size_t)255; return r; };
    const size_t NA = (size_t)NNODES * 512;            // 25.6M elems
    char* regionA = carve(NA * 2 * 2);                 // 102.4 MB
    char* regionB = carve(NA * 2 * 2);                 // 102.4 MB
    float* Xt1 = (float*)carve((size_t)NNODES * 256 * 4);  // 51.2 MB (lives across both signs)

    ushort_t* h0H = (ushort_t*)regionA; ushort_t* h0L = h0H + NA;
    ushort_t* h1H = (ushort_t*)regionB; ushort_t* h1L = h1H + NA;
    ushort_t* featH = h0H;  ushort_t* featL = h0L;         // G2 output overwrites h0
    float*    Y1  = (float*)regionB;                       // after Gt1, h1 dead
    ushort_t* X1H = (ushort_t*)regionA;                    // after Gt1, feat dead
    ushort_t* X1L = X1H + (size_t)NNODES * 256;
    float*    Xt2 = (float*)(regionA + (size_t)NNODES * 256 * 2 * 2);

    ushort_t* W0tH  = (ushort_t*)carve((size_t)512 * 2816 * 2);
    ushort_t* W0tL  = (ushort_t*)carve((size_t)512 * 2816 * 2);
    ushort_t* W1tH  = (ushort_t*)carve((size_t)512 * 512 * 2);
    ushort_t* W1tL  = (ushort_t*)carve((size_t)512 * 512 * 2);
    ushort_t* W2tH  = (ushort_t*)carve((size_t)512 * 512 * 2);
    ushort_t* W2tL  = (ushort_t*)carve((size_t)512 * 512 * 2);
    ushort_t* Wt1tH = (ushort_t*)carve((size_t)256 * 512 * 2);
    ushort_t* Wt1tL = (ushort_t*)carve((size_t)256 * 512 * 2);
    ushort_t* Wt2tH = (ushort_t*)carve((size_t)128 * 256 * 2);
    ushort_t* Wt2tL = (ushort_t*)carve((size_t)128 * 256 * 2);
    int* e_off  = (int*)carve((size_t)(NEDGES + 1) * 4);
    int* v_off  = (int*)carve((size_t)(NNODES + 1) * 4);
    int* e_by_v = (int*)carve((size_t)NP * 4);
    int* v_cnt  = (int*)carve((size_t)NNODES * 4);

    const int MB = (NNODES + 127) / 128; // 391

    // ---- weight prep ----
    transp_split<<<dim3(16, 88), 256, 0, stream>>>(W0, W0tH, W0tL, 2816, 512);
    transp_split<<<dim3(16, 16), 256, 0, stream>>>(W1, W1tH, W1tL, 512, 512);
    transp_split<<<dim3(16, 16), 256, 0, stream>>>(W2, W2tH, W2tL, 512, 512);
    transp_split<<<dim3(8, 16),  256, 0, stream>>>(Wt1, Wt1tH, Wt1tL, 512, 256);
    transp_split<<<dim3(4, 8),   256, 0, stream>>>(Wt2, Wt2tH, Wt2tL, 256, 128);

    // ---- MLP ----
    gemm_bf3<true, true, false, true><<<dim3(4, MB), 256, 0, stream>>>(
        m_emb, nullptr, nullptr, W0tH, W0tL, b0, nullptr, h0H, h0L, NNODES, 512, 2816);
    gemm_bf3<false, true, false, true><<<dim3(4, MB), 256, 0, stream>>>(
        nullptr, h0H, h0L, W1tH, W1tL, b1, nullptr, h1H, h1L, NNODES, 512, 512);
    gemm_bf3<false, false, false, true><<<dim3(4, MB), 256, 0, stream>>>(
        nullptr, h1H, h1L, W2tH, W2tL, b2, nullptr, featH, featL, NNODES, 512, 512);

    // ---- layer-1 dense is identical for both signs: compute Xt1 once ----
    gemm_bf3<false, false, true, false><<<dim3(2, MB), 256, 0, stream>>>(
        nullptr, featH, featL, Wt1tH, Wt1tL, bt1, Xt1, nullptr, nullptr, NNODES, 256, 512);

    auto do_sign = [&](const int* v_idx, const int* e_idx, float* outX, float* outY) {
        // CSR build: edge side from sortedness; vertex side via counting sort
        edge_off_sorted<<<2048, 256, 0, stream>>>(e_idx, NP, e_off, NEDGES);
        hipMemsetAsync(v_cnt, 0, (size_t)NNODES * 4, stream);
        hist_kernel<<<2048, 256, 0, stream>>>(v_idx, NP, v_cnt);
        exscan<<<1, 1024, 0, stream>>>(v_cnt, v_off, NNODES);
        scatter_kernel<<<2048, 256, 0, stream>>>(v_idx, e_idx, NP, v_off, v_cnt, e_by_v);

        // layer 1 aggregation
        seg_mean<256, false, true, false><<<(NEDGES + 3) / 4, 256, 0, stream>>>(
            Xt1, v_idx, e_off, Y1, nullptr, nullptr, NEDGES);
        seg_mean<256, true, false, true><<<(NNODES + 3) / 4, 256, 0, stream>>>(
            Y1, e_by_v, v_off, nullptr, X1H, X1L, NNODES);

        // layer 2
        gemm_bf3<false, false, true, false><<<dim3(1, MB), 256, 0, stream>>>(
            nullptr, X1H, X1L, Wt2tH, Wt2tL, bt2, Xt2, nullptr, nullptr, NNODES, 128, 256);
        seg_mean<128, false, true, false><<<(NEDGES + 3) / 4, 256, 0, stream>>>(
            Xt2, v_idx, e_off, outY, nullptr, nullptr, NEDGES);
        seg_mean<128, false, true, false><<<(NNODES + 3) / 4, 256, 0, stream>>>(
            outY, e_by_v, v_off, outX, nullptr, nullptr, NNODES);
    };

    // out layout: X1 [50000*128], X2 [50000*128], Y_pos [100000*128], Y_neg [100000*128]
    do_sign(v_pos, e_pos, out,           out + 12800000);
    do_sign(v_neg, e_neg, out + 6400000, out + 25600000);
}

// Round 4
// 2256.848 us; speedup vs baseline: 2.9010x; 1.2938x over previous
//
#include <hip/hip_runtime.h>

#define NP 1600000
#define NNODES 50000
#define NEDGES 100000

typedef short bf16x8 __attribute__((ext_vector_type(8)));
typedef short short4b __attribute__((ext_vector_type(4)));
typedef float f32x4 __attribute__((ext_vector_type(4)));
typedef unsigned short ushort_t;

static __device__ __forceinline__ ushort_t f2bf_rne(float f) {
    __bf16 b = (__bf16)f;                       // RNE, compiler emits v_cvt_pk_bf16_f32
    return __builtin_bit_cast(ushort_t, b);
}
static __device__ __forceinline__ float bf2f(ushort_t h) {
    union { float f; unsigned int u; } v; v.u = ((unsigned int)h) << 16;
    return v.f;
}

static __device__ __forceinline__ void gload_lds16(const void* g, void* lds) {
    __builtin_amdgcn_global_load_lds(
        (const __attribute__((address_space(1))) unsigned int*)g,
        (__attribute__((address_space(3))) unsigned int*)lds, 16, 0, 0);
}

// ---------------- bf16x3 split MFMA GEMM ------------------------------------
// C = A @ B + bias.  A [M,K] (f32 or bf16 hi/lo), B transposed [N,K] bf16 hi/lo.
// BM=BN=128, BK=32, 4 waves x (64x64), 16x16x32 MFMA, split-3 (AhBh+AhBl+AlBh).
// LDS kg-plane padded to 129 rows: staging ds_writes conflict-free, gload_lds
// destinations stay linear within a plane (row stride 16B).
// EPI: 0 = f32 out, 1 = bf16 out, 2 = bf16 hi/lo split out.
template<bool AF32, bool DORELU, int EPI>
__global__ __launch_bounds__(256, 2) void gemm_bf3(
    const float* __restrict__ Af,
    const ushort_t* __restrict__ Ah, const ushort_t* __restrict__ Al,
    const ushort_t* __restrict__ Bth, const ushort_t* __restrict__ Btl,
    const float* __restrict__ bias,
    float* __restrict__ Cf, ushort_t* __restrict__ Cb,
    ushort_t* __restrict__ Ch, ushort_t* __restrict__ Cl,
    int M, int N, int K)
{
    __shared__ ushort_t AsH[4][129][8];
    __shared__ ushort_t AsL[4][129][8];
    __shared__ ushort_t BsH[4][129][8];
    __shared__ ushort_t BsL[4][129][8];

    const int tid = threadIdx.x;
    const int wid = tid >> 6;
    const int lane = tid & 63;
    const int bn0 = blockIdx.x * 128;
    const int bm0 = blockIdx.y * 128;
    const int wrow0 = (wid >> 1) * 64;
    const int wcol0 = (wid & 1) * 64;

    f32x4 acc[4][4];
#pragma unroll
    for (int i = 0; i < 4; ++i)
#pragma unroll
        for (int j = 0; j < 4; ++j) acc[i][j] = (f32x4)0.f;

    const int nk = K >> 5;
    const int kgl = lane >> 4;
    const int r16 = lane & 15;

    // AF32 A-staging geometry (register prefetch pipeline)
    const int a_kq   = tid & 7;
    const int a_row0 = tid >> 3;
    const float* aBase[4];
    float4 aPre[4];
    if constexpr (AF32) {
#pragma unroll
        for (int cch = 0; cch < 4; ++cch) {
            int row = cch * 32 + a_row0;
            int r = bm0 + row; if (r > M - 1) r = M - 1;
            aBase[cch] = Af + (size_t)r * K + a_kq * 4;
            aPre[cch] = *(const float4*)(aBase[cch]);
        }
    }

    for (int kt = 0; kt < nk; ++kt) {
        __syncthreads();
        // ---- stage B (async direct-to-LDS) ----
#pragma unroll
        for (int h = 0; h < 2; ++h) {
            int c = bn0 + h * 64 + lane;
            const ushort_t* gbh = Bth + (size_t)c * K + kt * 32 + wid * 8;
            const ushort_t* gbl = Btl + (size_t)c * K + kt * 32 + wid * 8;
            gload_lds16(gbh, &BsH[wid][h * 64][0]);
            gload_lds16(gbl, &BsL[wid][h * 64][0]);
        }
        // ---- stage A ----
        if constexpr (AF32) {
#pragma unroll
            for (int cch = 0; cch < 4; ++cch) {
                int row = cch * 32 + a_row0;
                float4 v = aPre[cch];
                short4b hi, lo;
                ushort_t h0 = f2bf_rne(v.x), h1 = f2bf_rne(v.y);
                ushort_t h2 = f2bf_rne(v.z), h3 = f2bf_rne(v.w);
                hi[0] = (short)h0; hi[1] = (short)h1; hi[2] = (short)h2; hi[3] = (short)h3;
                lo[0] = (short)f2bf_rne(v.x - bf2f(h0));
                lo[1] = (short)f2bf_rne(v.y - bf2f(h1));
                lo[2] = (short)f2bf_rne(v.z - bf2f(h2));
                lo[3] = (short)f2bf_rne(v.w - bf2f(h3));
                int kg = a_kq >> 1, j0 = (a_kq & 1) * 4;
                *(short4b*)&AsH[kg][row][j0] = hi;
                *(short4b*)&AsL[kg][row][j0] = lo;
            }
        } else {
#pragma unroll
            for (int h = 0; h < 2; ++h) {
                int r = bm0 + h * 64 + lane; if (r > M - 1) r = M - 1;
                const ushort_t* gah = Ah + (size_t)r * K + kt * 32 + wid * 8;
                const ushort_t* gal = Al + (size_t)r * K + kt * 32 + wid * 8;
                gload_lds16(gah, &AsH[wid][h * 64][0]);
                gload_lds16(gal, &AsL[wid][h * 64][0]);
            }
        }
        __syncthreads();

        // issue next A f32 loads; latency hides under MFMA
        if constexpr (AF32) {
            if (kt + 1 < nk) {
#pragma unroll
                for (int cch = 0; cch < 4; ++cch)
                    aPre[cch] = *(const float4*)(aBase[cch] + (kt + 1) * 32);
            }
        }

        bf16x8 ah[4], al[4], bh[4], bl[4];
#pragma unroll
        for (int mi = 0; mi < 4; ++mi) {
            ah[mi] = *(const bf16x8*)&AsH[kgl][wrow0 + mi * 16 + r16][0];
            al[mi] = *(const bf16x8*)&AsL[kgl][wrow0 + mi * 16 + r16][0];
        }
#pragma unroll
        for (int ni = 0; ni < 4; ++ni) {
            bh[ni] = *(const bf16x8*)&BsH[kgl][wcol0 + ni * 16 + r16][0];
            bl[ni] = *(const bf16x8*)&BsL[kgl][wcol0 + ni * 16 + r16][0];
        }
#pragma unroll
        for (int mi = 0; mi < 4; ++mi)
#pragma unroll
            for (int ni = 0; ni < 4; ++ni) {
                acc[mi][ni] = __builtin_amdgcn_mfma_f32_16x16x32_bf16(ah[mi], bh[ni], acc[mi][ni], 0, 0, 0);
                acc[mi][ni] = __builtin_amdgcn_mfma_f32_16x16x32_bf16(ah[mi], bl[ni], acc[mi][ni], 0, 0, 0);
                acc[mi][ni] = __builtin_amdgcn_mfma_f32_16x16x32_bf16(al[mi], bh[ni], acc[mi][ni], 0, 0, 0);
            }
    }

    // ---- epilogue: C/D layout col=lane&15 (N), row=(lane>>4)*4+reg (M) ----
    const int rg4 = (lane >> 4) * 4;
#pragma unroll
    for (int ni = 0; ni < 4; ++ni) {
        int gcol = bn0 + wcol0 + ni * 16 + r16;
        float bb = bias[gcol];
#pragma unroll
        for (int mi = 0; mi < 4; ++mi)
#pragma unroll
            for (int rg = 0; rg < 4; ++rg) {
                int grow = bm0 + wrow0 + mi * 16 + rg4 + rg;
                if (grow < M) {
                    float v = acc[mi][ni][rg] + bb;
                    if constexpr (DORELU) v = fmaxf(v, 0.f);
                    if constexpr (EPI == 0) {
                        Cf[(size_t)grow * N + gcol] = v;
                    } else if constexpr (EPI == 1) {
                        Cb[(size_t)grow * N + gcol] = f2bf_rne(v);
                    } else {
                        ushort_t h = f2bf_rne(v);
                        Ch[(size_t)grow * N + gcol] = h;
                        Cl[(size_t)grow * N + gcol] = f2bf_rne(v - bf2f(h));
                    }
                }
            }
    }
}

// ---------------- weight transpose + split: W[K,N] f32 -> Bt hi/lo [N,K] ----
__global__ __launch_bounds__(256) void transp_split(
    const float* __restrict__ W, ushort_t* __restrict__ BtH, ushort_t* __restrict__ BtL,
    int K, int N)
{
    __shared__ float T[32][33];
    const int n0 = blockIdx.x * 32, k0 = blockIdx.y * 32;
    const int c = threadIdx.x & 31, r8 = threadIdx.x >> 5;
#pragma unroll
    for (int i = 0; i < 4; ++i) {
        int kr = r8 + i * 8;
        T[kr][c] = W[(size_t)(k0 + kr) * N + n0 + c];
    }
    __syncthreads();
#pragma unroll
    for (int i = 0; i < 4; ++i) {
        int nr = r8 + i * 8;
        float v = T[c][nr];
        ushort_t h = f2bf_rne(v);
        BtH[(size_t)(n0 + nr) * K + k0 + c] = h;
        BtL[(size_t)(n0 + nr) * K + k0 + c] = f2bf_rne(v - bf2f(h));
    }
}

// ---------------- CSR builders (both signs, sign = blockIdx.y) --------------
__global__ void edge_off_both(const int* __restrict__ ePos, const int* __restrict__ eNeg,
                              int* __restrict__ off)
{
    const int sign = blockIdx.y;
    const int* e_idx = sign ? eNeg : ePos;
    int* o = off + sign * (NEDGES + 1);
    int i = blockIdx.x * blockDim.x + threadIdx.x;
    int stride = gridDim.x * blockDim.x;
    for (; i < NP; i += stride) {
        int cur = e_idx[i];
        int prev = (i > 0) ? e_idx[i - 1] : -1;
        for (int e = prev + 1; e <= cur; ++e) o[e] = i;
        if (i == NP - 1)
            for (int e = cur + 1; e <= NEDGES; ++e) o[e] = NP;
    }
}

__global__ void hist_both(const int* __restrict__ vPos, const int* __restrict__ vNeg,
                          int* __restrict__ cnt)
{
    const int sign = blockIdx.y;
    const int* v = sign ? vNeg : vPos;
    int* c = cnt + sign * NNODES;
    int i = blockIdx.x * blockDim.x + threadIdx.x;
    int stride = gridDim.x * blockDim.x;
    for (; i < NP; i += stride) atomicAdd(&c[v[i]], 1);
}

__global__ __launch_bounds__(1024) void exscan2(const int* __restrict__ cnt,
                                                int* __restrict__ off)
{
    const int sign = blockIdx.x;
    const int* c = cnt + sign * NNODES;
    int* o = off + sign * (NNODES + 1);
    __shared__ int sums[1024];
    const int t = threadIdx.x;
    const int per = (NNODES + 1023) >> 10;
    const int b = t * per;
    const int e = min(b + per, NNODES);
    int s = 0;
    for (int i = b; i < e; ++i) s += c[i];
    sums[t] = s;
    __syncthreads();
    for (int d = 1; d < 1024; d <<= 1) {
        int v = (t >= d) ? sums[t - d] : 0;
        __syncthreads();
        sums[t] += v;
        __syncthreads();
    }
    int run = (t > 0) ? sums[t - 1] : 0;
    for (int i = b; i < e; ++i) { o[i] = run; run += c[i]; }
    if (t == 1023) o[NNODES] = run;
}

__global__ void scatter_both(const int* __restrict__ vPos, const int* __restrict__ vNeg,
                             const int* __restrict__ ePos, const int* __restrict__ eNeg,
                             const int* __restrict__ v_off, int* __restrict__ v_cnt,
                             int* __restrict__ e_by_v)
{
    const int sign = blockIdx.y;
    const int* v_idx = sign ? vNeg : vPos;
    const int* e_idx = sign ? eNeg : ePos;
    const int* vo = v_off + sign * (NNODES + 1);
    int* vc = v_cnt + sign * NNODES;
    int* ebv = e_by_v + sign * NP;
    int i = blockIdx.x * blockDim.x + threadIdx.x;
    int stride = gridDim.x * blockDim.x;
    for (; i < NP; i += stride) {
        int v = v_idx[i];
        int pos = atomicSub(&vc[v], 1) - 1;
        ebv[vo[v] + pos] = e_idx[i];
    }
}

// ---------------- segment mean, dual-sign, 16B/lane, multi-member/iter ------
// SRCBF: source bf16; C channels; EPI: 0 f32 out, 1 bf16 out, 2 hi/lo split.
template<bool SRCBF, int C, bool DORELU, int EPI>
__global__ __launch_bounds__(256) void seg_mean2(
    const void* __restrict__ src, long long src_stride,
    const int* __restrict__ idx0, const int* __restrict__ idx1,
    const int* __restrict__ off_base, int off_stride,
    float* __restrict__ dstf, long long dstf_stride,
    ushort_t* __restrict__ dB, long long dB_stride,
    ushort_t* __restrict__ dH, ushort_t* __restrict__ dL, long long hl_stride,
    int nseg)
{
    constexpr int ES  = SRCBF ? 2 : 4;
    constexpr int ROWB = C * ES;
    constexpr int LPR = ROWB / 16;        // lanes covering one row
    constexpr int MPI = 64 / LPR;         // members per wave-iteration
    constexpr int CPL = 16 / ES;          // channels per lane

    const int sign = blockIdx.y;
    const int* idx = sign ? idx1 : idx0;
    const int* off = off_base + sign * off_stride;

    const int wave = threadIdx.x >> 6, lane = threadIdx.x & 63;
    const int s = blockIdx.x * 4 + wave;
    if (s >= nseg) return;
    const int b = off[s], e = off[s + 1];
    const int sub = lane / LPR;
    const int cl  = lane % LPR;
    const int cbase = cl * CPL;

    float acc[CPL];
#pragma unroll
    for (int k = 0; k < CPL; ++k) acc[k] = 0.f;

    if constexpr (SRCBF) {
        const ushort_t* sp = (const ushort_t*)src + sign * src_stride;
#pragma unroll 2
        for (int j = b + sub; j < e; j += MPI) {
            int row = idx[j];
            uint4 u = *(const uint4*)(sp + (size_t)row * C + cbase);
            unsigned int uu[4] = {u.x, u.y, u.z, u.w};
#pragma unroll
            for (int q = 0; q < 4; ++q) {
                union { float f; unsigned int v; } lo, hi;
                lo.v = uu[q] << 16; hi.v = uu[q] & 0xffff0000u;
                acc[q * 2]     += lo.f;
                acc[q * 2 + 1] += hi.f;
            }
        }
    } else {
        const float* sp = (const float*)src + sign * src_stride;
#pragma unroll 2
        for (int j = b + sub; j < e; j += MPI) {
            int row = idx[j];
            float4 v = *(const float4*)(sp + (size_t)row * C + cbase);
            acc[0] += v.x; acc[1] += v.y; acc[2] += v.z; acc[3] += v.w;
        }
    }

    // butterfly-reduce across member slots
#pragma unroll
    for (int st = LPR; st < 64; st <<= 1)
#pragma unroll
        for (int k = 0; k < CPL; ++k)
            acc[k] += __shfl_xor(acc[k], st);

    if (lane < LPR) {
        const float inv = 1.f / fmaxf((float)(e - b), 1.f);
#pragma unroll
        for (int k = 0; k < CPL; ++k) {
            float v = acc[k] * inv;
            if constexpr (DORELU) v = fmaxf(v, 0.f);
            if constexpr (EPI == 0) {
                (dstf + sign * dstf_stride)[(size_t)s * C + cbase + k] = v;
            } else if constexpr (EPI == 1) {
                (dB + sign * dB_stride)[(size_t)s * C + cbase + k] = f2bf_rne(v);
            } else {
                ushort_t h = f2bf_rne(v);
                (dH + sign * hl_stride)[(size_t)s * C + cbase + k] = h;
                (dL + sign * hl_stride)[(size_t)s * C + cbase + k] = f2bf_rne(v - bf2f(h));
            }
        }
    }
}

extern "C" void kernel_launch(void* const* d_in, const int* in_sizes, int n_in,
                              void* d_out, int out_size, void* d_ws, size_t ws_size,
                              hipStream_t stream)
{
    const float* m_emb = (const float*)d_in[0];
    const int*   v_pos = (const int*)d_in[1];
    const int*   e_pos = (const int*)d_in[2];
    const int*   v_neg = (const int*)d_in[3];
    const int*   e_neg = (const int*)d_in[4];
    const float* W0  = (const float*)d_in[5];
    const float* b0  = (const float*)d_in[6];
    const float* W1  = (const float*)d_in[7];
    const float* b1  = (const float*)d_in[8];
    const float* W2  = (const float*)d_in[9];
    const float* b2  = (const float*)d_in[10];
    const float* Wt1 = (const float*)d_in[11];
    const float* bt1 = (const float*)d_in[12];
    const float* Wt2 = (const float*)d_in[13];
    const float* bt2 = (const float*)d_in[14];
    float* out = (float*)d_out;

    // ---- workspace carve (~278 MB) ----
    char* p = (char*)d_ws;
    auto carve = [&](size_t bytes) { char* r = p; p += (bytes + 255) & ~(size_t)255; return r; };
    const size_t NA = (size_t)NNODES * 512;                // 25.6M elems
    char* regionA = carve(NA * 2 * 2);                     // 102.4 MB
    char* regionB = carve(NA * 2 * 2);                     // 102.4 MB
    ushort_t* Xt1b = (ushort_t*)carve((size_t)NNODES * 256 * 2);       // 25.6 MB
    ushort_t* Xt2b = (ushort_t*)carve((size_t)2 * NNODES * 128 * 2);   // 25.6 MB

    ushort_t* h0H = (ushort_t*)regionA; ushort_t* h0L = h0H + NA;
    ushort_t* h1H = (ushort_t*)regionB; ushort_t* h1L = h1H + NA;
    ushort_t* featH = h0H;  ushort_t* featL = h0L;          // G2 overwrites h0
    ushort_t* Y1b  = (ushort_t*)regionB;                    // [2][100000][256], h1 dead
    ushort_t* X1H  = (ushort_t*)regionA;                    // [2*50000][256], feat dead
    ushort_t* X1L  = X1H + (size_t)2 * NNODES * 256;

    ushort_t* W0tH  = (ushort_t*)carve((size_t)512 * 2816 * 2);
    ushort_t* W0tL  = (ushort_t*)carve((size_t)512 * 2816 * 2);
    ushort_t* W1tH  = (ushort_t*)carve((size_t)512 * 512 * 2);
    ushort_t* W1tL  = (ushort_t*)carve((size_t)512 * 512 * 2);
    ushort_t* W2tH  = (ushort_t*)carve((size_t)512 * 512 * 2);
    ushort_t* W2tL  = (ushort_t*)carve((size_t)512 * 512 * 2);
    ushort_t* Wt1tH = (ushort_t*)carve((size_t)256 * 512 * 2);
    ushort_t* Wt1tL = (ushort_t*)carve((size_t)256 * 512 * 2);
    ushort_t* Wt2tH = (ushort_t*)carve((size_t)128 * 256 * 2);
    ushort_t* Wt2tL = (ushort_t*)carve((size_t)128 * 256 * 2);
    int* e_off  = (int*)carve((size_t)2 * (NEDGES + 1) * 4);
    int* v_off  = (int*)carve((size_t)2 * (NNODES + 1) * 4);
    int* e_by_v = (int*)carve((size_t)2 * NP * 4);
    int* v_cnt  = (int*)carve((size_t)2 * NNODES * 4);

    const int MB = (NNODES + 127) / 128;       // 391
    const int MB2 = (2 * NNODES + 127) / 128;  // 782

    // ---- weight prep ----
    transp_split<<<dim3(16, 88), 256, 0, stream>>>(W0, W0tH, W0tL, 2816, 512);
    transp_split<<<dim3(16, 16), 256, 0, stream>>>(W1, W1tH, W1tL, 512, 512);
    transp_split<<<dim3(16, 16), 256, 0, stream>>>(W2, W2tH, W2tL, 512, 512);
    transp_split<<<dim3(8, 16),  256, 0, stream>>>(Wt1, Wt1tH, Wt1tL, 512, 256);
    transp_split<<<dim3(4, 8),   256, 0, stream>>>(Wt2, Wt2tH, Wt2tL, 256, 128);

    // ---- CSR for both signs ----
    edge_off_both<<<dim3(1024, 2), 256, 0, stream>>>(e_pos, e_neg, e_off);
    hipMemsetAsync(v_cnt, 0, (size_t)2 * NNODES * 4, stream);
    hist_both<<<dim3(1024, 2), 256, 0, stream>>>(v_pos, v_neg, v_cnt);
    exscan2<<<2, 1024, 0, stream>>>(v_cnt, v_off);
    scatter_both<<<dim3(1024, 2), 256, 0, stream>>>(v_pos, v_neg, e_pos, e_neg,
                                                    v_off, v_cnt, e_by_v);

    // ---- MLP ----
    gemm_bf3<true, true, 2><<<dim3(4, MB), 256, 0, stream>>>(
        m_emb, nullptr, nullptr, W0tH, W0tL, b0, nullptr, nullptr, h0H, h0L, NNODES, 512, 2816);
    gemm_bf3<false, true, 2><<<dim3(4, MB), 256, 0, stream>>>(
        nullptr, h0H, h0L, W1tH, W1tL, b1, nullptr, nullptr, h1H, h1L, NNODES, 512, 512);
    gemm_bf3<false, false, 2><<<dim3(4, MB), 256, 0, stream>>>(
        nullptr, h1H, h1L, W2tH, W2tL, b2, nullptr, nullptr, featH, featL, NNODES, 512, 512);

    // ---- layer-1 dense (shared by both signs) ----
    gemm_bf3<false, false, 1><<<dim3(2, MB), 256, 0, stream>>>(
        nullptr, featH, featL, Wt1tH, Wt1tL, bt1, nullptr, Xt1b, nullptr, nullptr, NNODES, 256, 512);

    // ---- layer-1 aggregation, both signs ----
    seg_mean2<true, 256, false, 1><<<dim3(NEDGES / 4, 2), 256, 0, stream>>>(
        Xt1b, 0, v_pos, v_neg, e_off, NEDGES + 1,
        nullptr, 0, Y1b, (long long)NEDGES * 256, nullptr, nullptr, 0, NEDGES);
    seg_mean2<true, 256, true, 2><<<dim3(NNODES / 4, 2), 256, 0, stream>>>(
        Y1b, (long long)NEDGES * 256, e_by_v, e_by_v + NP, v_off, NNODES + 1,
        nullptr, 0, nullptr, 0, X1H, X1L, (long long)NNODES * 256, NNODES);

    // ---- layer-2 dense: one GEMM over both signs (M = 100000) ----
    gemm_bf3<false, false, 1><<<dim3(1, MB2), 256, 0, stream>>>(
        nullptr, X1H, X1L, Wt2tH, Wt2tL, bt2, nullptr, Xt2b, nullptr, nullptr, 2 * NNODES, 128, 256);

    // ---- layer-2 aggregation, both signs ----
    // out layout: X1 [50000*128] @0, X2 @6.4M, Y_pos [100000*128] @12.8M, Y_neg @25.6M
    seg_mean2<true, 128, false, 0><<<dim3(NEDGES / 4, 2), 256, 0, stream>>>(
        Xt2b, (long long)NNODES * 128, v_pos, v_neg, e_off, NEDGES + 1,
        out + 12800000, 12800000LL, nullptr, 0, nullptr, nullptr, 0, NEDGES);
    seg_mean2<false, 128, false, 0><<<dim3(NNODES / 4, 2), 256, 0, stream>>>(
        out + 12800000, 12800000LL, e_by_v, e_by_v + NP, v_off, NNODES + 1,
        out, 6400000LL, nullptr, 0, nullptr, nullptr, 0, NNODES);
}

// Round 5
// 2156.752 us; speedup vs baseline: 3.0356x; 1.0464x over previous
//
#include <hip/hip_runtime.h>

#define NP 1600000
#define NNODES 50000
#define NEDGES 100000

typedef short bf16x8 __attribute__((ext_vector_type(8)));
typedef short short4b __attribute__((ext_vector_type(4)));
typedef float f32x4 __attribute__((ext_vector_type(4)));
typedef unsigned short ushort_t;

static __device__ __forceinline__ ushort_t f2bf_rne(float f) {
    __bf16 b = (__bf16)f;
    return __builtin_bit_cast(ushort_t, b);
}
static __device__ __forceinline__ float bf2f(ushort_t h) {
    union { float f; unsigned int u; } v; v.u = ((unsigned int)h) << 16;
    return v.f;
}
static __device__ __forceinline__ void addbf8(float* a, uint4 u) {
    unsigned int uu[4] = {u.x, u.y, u.z, u.w};
#pragma unroll
    for (int q = 0; q < 4; ++q) {
        union { float f; unsigned int v; } lo, hi;
        lo.v = uu[q] << 16; hi.v = uu[q] & 0xffff0000u;
        a[2 * q]     += lo.f;
        a[2 * q + 1] += hi.f;
    }
}

static __device__ __forceinline__ void gload_lds16(const void* g, void* lds) {
    __builtin_amdgcn_global_load_lds(
        (const __attribute__((address_space(1))) unsigned int*)g,
        (__attribute__((address_space(3))) unsigned int*)lds, 16, 0, 0);
}

// ---------------- bf16x3 split MFMA GEMM ------------------------------------
// C = A @ B + bias.  A [M,K] (f32 or bf16 hi/lo), B transposed [N,K] bf16 hi/lo.
// BM=BN=128, BK=32, 4 waves x (64x64), 16x16x32 MFMA, split-3 (AhBh+AhBl+AlBh).
// XCD-chunked bijective block swizzle (T1/m204): each XCD gets a contiguous
// run of row-major tiles -> col-blocks sharing an A row-panel share one L2.
// EPI: 0 = f32 out, 1 = bf16 out, 2 = bf16 hi/lo split out.
template<bool AF32, bool DORELU, int EPI>
__global__ __launch_bounds__(256, 3) void gemm_bf3(
    const float* __restrict__ Af,
    const ushort_t* __restrict__ Ah, const ushort_t* __restrict__ Al,
    const ushort_t* __restrict__ Bth, const ushort_t* __restrict__ Btl,
    const float* __restrict__ bias,
    float* __restrict__ Cf, ushort_t* __restrict__ Cb,
    ushort_t* __restrict__ Ch, ushort_t* __restrict__ Cl,
    int M, int N, int K)
{
    __shared__ ushort_t AsH[4][129][8];
    __shared__ ushort_t AsL[4][129][8];
    __shared__ ushort_t BsH[4][129][8];
    __shared__ ushort_t BsL[4][129][8];

    const int tid = threadIdx.x;
    const int wid = tid >> 6;
    const int lane = tid & 63;

    // bijective XCD-chunked swizzle
    const int nwg = gridDim.x * gridDim.y;
    const int wg  = blockIdx.y * gridDim.x + blockIdx.x;
    const int q = nwg >> 3, r = nwg & 7;
    const int xcd = wg & 7, loc = wg >> 3;
    const int swz = (xcd < r) ? (xcd * (q + 1) + loc)
                              : (r * (q + 1) + (xcd - r) * q + loc);
    const int bn0 = (int)(swz % gridDim.x) * 128;
    const int bm0 = (int)(swz / gridDim.x) * 128;

    const int wrow0 = (wid >> 1) * 64;
    const int wcol0 = (wid & 1) * 64;

    f32x4 acc[4][4];
#pragma unroll
    for (int i = 0; i < 4; ++i)
#pragma unroll
        for (int j = 0; j < 4; ++j) acc[i][j] = (f32x4)0.f;

    const int nk = K >> 5;
    const int kgl = lane >> 4;
    const int r16 = lane & 15;

    // AF32 A-staging geometry (register prefetch pipeline)
    const int a_kq   = tid & 7;
    const int a_row0 = tid >> 3;
    const float* aBase[4];
    float4 aPre[4];
    if constexpr (AF32) {
#pragma unroll
        for (int cch = 0; cch < 4; ++cch) {
            int row = cch * 32 + a_row0;
            int rr = bm0 + row; if (rr > M - 1) rr = M - 1;
            aBase[cch] = Af + (size_t)rr * K + a_kq * 4;
            aPre[cch] = *(const float4*)(aBase[cch]);
        }
    }

    for (int kt = 0; kt < nk; ++kt) {
        __syncthreads();
        // ---- stage B (async direct-to-LDS) ----
#pragma unroll
        for (int h = 0; h < 2; ++h) {
            int c = bn0 + h * 64 + lane;
            const ushort_t* gbh = Bth + (size_t)c * K + kt * 32 + wid * 8;
            const ushort_t* gbl = Btl + (size_t)c * K + kt * 32 + wid * 8;
            gload_lds16(gbh, &BsH[wid][h * 64][0]);
            gload_lds16(gbl, &BsL[wid][h * 64][0]);
        }
        // ---- stage A ----
        if constexpr (AF32) {
#pragma unroll
            for (int cch = 0; cch < 4; ++cch) {
                int row = cch * 32 + a_row0;
                float4 v = aPre[cch];
                short4b hi, lo;
                ushort_t h0 = f2bf_rne(v.x), h1 = f2bf_rne(v.y);
                ushort_t h2 = f2bf_rne(v.z), h3 = f2bf_rne(v.w);
                hi[0] = (short)h0; hi[1] = (short)h1; hi[2] = (short)h2; hi[3] = (short)h3;
                lo[0] = (short)f2bf_rne(v.x - bf2f(h0));
                lo[1] = (short)f2bf_rne(v.y - bf2f(h1));
                lo[2] = (short)f2bf_rne(v.z - bf2f(h2));
                lo[3] = (short)f2bf_rne(v.w - bf2f(h3));
                int kg = a_kq >> 1, j0 = (a_kq & 1) * 4;
                *(short4b*)&AsH[kg][row][j0] = hi;
                *(short4b*)&AsL[kg][row][j0] = lo;
            }
        } else {
#pragma unroll
            for (int h = 0; h < 2; ++h) {
                int rr = bm0 + h * 64 + lane; if (rr > M - 1) rr = M - 1;
                const ushort_t* gah = Ah + (size_t)rr * K + kt * 32 + wid * 8;
                const ushort_t* gal = Al + (size_t)rr * K + kt * 32 + wid * 8;
                gload_lds16(gah, &AsH[wid][h * 64][0]);
                gload_lds16(gal, &AsL[wid][h * 64][0]);
            }
        }
        __syncthreads();

        // issue next A f32 loads; latency hides under MFMA
        if constexpr (AF32) {
            if (kt + 1 < nk) {
#pragma unroll
                for (int cch = 0; cch < 4; ++cch)
                    aPre[cch] = *(const float4*)(aBase[cch] + (kt + 1) * 32);
            }
        }

        bf16x8 ah[4], al[4], bh[4], bl[4];
#pragma unroll
        for (int mi = 0; mi < 4; ++mi) {
            ah[mi] = *(const bf16x8*)&AsH[kgl][wrow0 + mi * 16 + r16][0];
            al[mi] = *(const bf16x8*)&AsL[kgl][wrow0 + mi * 16 + r16][0];
        }
#pragma unroll
        for (int ni = 0; ni < 4; ++ni) {
            bh[ni] = *(const bf16x8*)&BsH[kgl][wcol0 + ni * 16 + r16][0];
            bl[ni] = *(const bf16x8*)&BsL[kgl][wcol0 + ni * 16 + r16][0];
        }
#pragma unroll
        for (int mi = 0; mi < 4; ++mi)
#pragma unroll
            for (int ni = 0; ni < 4; ++ni) {
                acc[mi][ni] = __builtin_amdgcn_mfma_f32_16x16x32_bf16(ah[mi], bh[ni], acc[mi][ni], 0, 0, 0);
                acc[mi][ni] = __builtin_amdgcn_mfma_f32_16x16x32_bf16(ah[mi], bl[ni], acc[mi][ni], 0, 0, 0);
                acc[mi][ni] = __builtin_amdgcn_mfma_f32_16x16x32_bf16(al[mi], bh[ni], acc[mi][ni], 0, 0, 0);
            }
    }

    // ---- epilogue: C/D layout col=lane&15 (N), row=(lane>>4)*4+reg (M) ----
    const int rg4 = (lane >> 4) * 4;
#pragma unroll
    for (int ni = 0; ni < 4; ++ni) {
        int gcol = bn0 + wcol0 + ni * 16 + r16;
        float bb = bias[gcol];
#pragma unroll
        for (int mi = 0; mi < 4; ++mi)
#pragma unroll
            for (int rg = 0; rg < 4; ++rg) {
                int grow = bm0 + wrow0 + mi * 16 + rg4 + rg;
                if (grow < M) {
                    float v = acc[mi][ni][rg] + bb;
                    if constexpr (DORELU) v = fmaxf(v, 0.f);
                    if constexpr (EPI == 0) {
                        Cf[(size_t)grow * N + gcol] = v;
                    } else if constexpr (EPI == 1) {
                        Cb[(size_t)grow * N + gcol] = f2bf_rne(v);
                    } else {
                        ushort_t h = f2bf_rne(v);
                        Ch[(size_t)grow * N + gcol] = h;
                        Cl[(size_t)grow * N + gcol] = f2bf_rne(v - bf2f(h));
                    }
                }
            }
    }
}

// ---------------- fused weight prep: all 5 weights in one launch ------------
__global__ __launch_bounds__(256) void prep_all(
    const float* __restrict__ W0, const float* __restrict__ W1,
    const float* __restrict__ W2, const float* __restrict__ Wt1,
    const float* __restrict__ Wt2,
    ushort_t* __restrict__ W0tH, ushort_t* __restrict__ W0tL,
    ushort_t* __restrict__ W1tH, ushort_t* __restrict__ W1tL,
    ushort_t* __restrict__ W2tH, ushort_t* __restrict__ W2tL,
    ushort_t* __restrict__ Wt1tH, ushort_t* __restrict__ Wt1tL,
    ushort_t* __restrict__ Wt2tH, ushort_t* __restrict__ Wt2tL)
{
    const int bsel = blockIdx.x;
    const float* W; ushort_t* H; ushort_t* L; int K, N, nx, rel;
    if (bsel < 1408)      { W = W0;  H = W0tH;  L = W0tL;  K = 2816; N = 512; nx = 16; rel = bsel; }
    else if (bsel < 1664) { W = W1;  H = W1tH;  L = W1tL;  K = 512;  N = 512; nx = 16; rel = bsel - 1408; }
    else if (bsel < 1920) { W = W2;  H = W2tH;  L = W2tL;  K = 512;  N = 512; nx = 16; rel = bsel - 1664; }
    else if (bsel < 2048) { W = Wt1; H = Wt1tH; L = Wt1tL; K = 512;  N = 256; nx = 8;  rel = bsel - 1920; }
    else                  { W = Wt2; H = Wt2tH; L = Wt2tL; K = 256;  N = 128; nx = 4;  rel = bsel - 2048; }
    const int n0 = (rel % nx) * 32, k0 = (rel / nx) * 32;

    __shared__ float T[32][33];
    const int c = threadIdx.x & 31, r8 = threadIdx.x >> 5;
#pragma unroll
    for (int i = 0; i < 4; ++i)
        T[r8 + i * 8][c] = W[(size_t)(k0 + r8 + i * 8) * N + n0 + c];
    __syncthreads();
#pragma unroll
    for (int i = 0; i < 4; ++i) {
        int nr = r8 + i * 8;
        float v = T[c][nr];
        ushort_t h = f2bf_rne(v);
        H[(size_t)(n0 + nr) * K + k0 + c] = h;
        L[(size_t)(n0 + nr) * K + k0 + c] = f2bf_rne(v - bf2f(h));
    }
}

// ---------------- fused CSR pass 1: edge offsets (sorted) + vertex hist -----
__global__ void build_csr1(const int* __restrict__ ePos, const int* __restrict__ eNeg,
                           const int* __restrict__ vPos, const int* __restrict__ vNeg,
                           int* __restrict__ e_off, int* __restrict__ v_cnt)
{
    const int sign = blockIdx.y;
    const int* e_idx = sign ? eNeg : ePos;
    const int* v_idx = sign ? vNeg : vPos;
    int* o  = e_off + sign * (NEDGES + 1);
    int* vc = v_cnt + sign * NNODES;
    int i = blockIdx.x * blockDim.x + threadIdx.x;
    int stride = gridDim.x * blockDim.x;
    for (; i < NP; i += stride) {
        int cur = e_idx[i];
        int prev = (i > 0) ? e_idx[i - 1] : -1;
        for (int e = prev + 1; e <= cur; ++e) o[e] = i;
        if (i == NP - 1)
            for (int e = cur + 1; e <= NEDGES; ++e) o[e] = NP;
        atomicAdd(&vc[v_idx[i]], 1);
    }
}

__global__ __launch_bounds__(1024) void exscan2(const int* __restrict__ cnt,
                                                int* __restrict__ off)
{
    const int sign = blockIdx.x;
    const int* c = cnt + sign * NNODES;
    int* o = off + sign * (NNODES + 1);
    __shared__ int sums[1024];
    const int t = threadIdx.x;
    const int per = (NNODES + 1023) >> 10;
    const int b = t * per;
    const int e = min(b + per, NNODES);
    int s = 0;
    for (int i = b; i < e; ++i) s += c[i];
    sums[t] = s;
    __syncthreads();
    for (int d = 1; d < 1024; d <<= 1) {
        int v = (t >= d) ? sums[t - d] : 0;
        __syncthreads();
        sums[t] += v;
        __syncthreads();
    }
    int run = (t > 0) ? sums[t - 1] : 0;
    for (int i = b; i < e; ++i) { o[i] = run; run += c[i]; }
    if (t == 1023) o[NNODES] = run;
}

__global__ void scatter_both(const int* __restrict__ vPos, const int* __restrict__ vNeg,
                             const int* __restrict__ ePos, const int* __restrict__ eNeg,
                             const int* __restrict__ v_off, int* __restrict__ v_cnt,
                             int* __restrict__ e_by_v)
{
    const int sign = blockIdx.y;
    const int* v_idx = sign ? vNeg : vPos;
    const int* e_idx = sign ? eNeg : ePos;
    const int* vo = v_off + sign * (NNODES + 1);
    int* vc = v_cnt + sign * NNODES;
    int* ebv = e_by_v + sign * NP;
    int i = blockIdx.x * blockDim.x + threadIdx.x;
    int stride = gridDim.x * blockDim.x;
    for (; i < NP; i += stride) {
        int v = v_idx[i];
        int pos = atomicSub(&vc[v], 1) - 1;
        ebv[vo[v] + pos] = e_idx[i];
    }
}

// ---------------- segment mean, dual-sign, 16B/lane, 4-wide gather ----------
// EPI: 0 f32 out, 1 bf16 out, 2 bf16 hi/lo split, 3 f32 out + bf16 shadow.
template<bool SRCBF, int C, bool DORELU, int EPI>
__global__ __launch_bounds__(256) void seg_mean2(
    const void* __restrict__ src, long long src_stride,
    const int* __restrict__ idx0, const int* __restrict__ idx1,
    const int* __restrict__ off_base, int off_stride,
    float* __restrict__ dstf, long long dstf_stride,
    ushort_t* __restrict__ dB, long long dB_stride,
    ushort_t* __restrict__ dH, ushort_t* __restrict__ dL, long long hl_stride,
    int nseg)
{
    constexpr int ES  = SRCBF ? 2 : 4;
    constexpr int LPR = (C * ES) / 16;    // lanes covering one row
    constexpr int MPI = 64 / LPR;         // members per wave-iteration
    constexpr int CPL = 16 / ES;          // channels per lane

    const int sign = blockIdx.y;
    const int* idx = sign ? idx1 : idx0;
    const int* off = off_base + (size_t)sign * off_stride;

    const int wave = threadIdx.x >> 6, lane = threadIdx.x & 63;
    const int s = blockIdx.x * 4 + wave;
    if (s >= nseg) return;
    const int b = off[s], e = off[s + 1];
    const int sub = lane / LPR;
    const int cbase = (lane % LPR) * CPL;

    float a0[CPL], a1[CPL], a2[CPL], a3[CPL];
#pragma unroll
    for (int k = 0; k < CPL; ++k) { a0[k] = 0.f; a1[k] = 0.f; a2[k] = 0.f; a3[k] = 0.f; }

    int j = b + sub;
    if constexpr (SRCBF) {
        const ushort_t* sp = (const ushort_t*)src + (size_t)sign * src_stride;
        for (; j + 3 * MPI < e; j += 4 * MPI) {
            int i0 = idx[j], i1 = idx[j + MPI], i2 = idx[j + 2 * MPI], i3 = idx[j + 3 * MPI];
            uint4 u0 = *(const uint4*)(sp + (size_t)i0 * C + cbase);
            uint4 u1 = *(const uint4*)(sp + (size_t)i1 * C + cbase);
            uint4 u2 = *(const uint4*)(sp + (size_t)i2 * C + cbase);
            uint4 u3 = *(const uint4*)(sp + (size_t)i3 * C + cbase);
            addbf8(a0, u0); addbf8(a1, u1); addbf8(a2, u2); addbf8(a3, u3);
        }
        for (; j < e; j += MPI) {
            uint4 u = *(const uint4*)(sp + (size_t)idx[j] * C + cbase);
            addbf8(a0, u);
        }
    } else {
        const float* sp = (const float*)src + (size_t)sign * src_stride;
        for (; j + 3 * MPI < e; j += 4 * MPI) {
            int i0 = idx[j], i1 = idx[j + MPI], i2 = idx[j + 2 * MPI], i3 = idx[j + 3 * MPI];
            float4 v0 = *(const float4*)(sp + (size_t)i0 * C + cbase);
            float4 v1 = *(const float4*)(sp + (size_t)i1 * C + cbase);
            float4 v2 = *(const float4*)(sp + (size_t)i2 * C + cbase);
            float4 v3 = *(const float4*)(sp + (size_t)i3 * C + cbase);
            a0[0] += v0.x; a0[1] += v0.y; a0[2] += v0.z; a0[3] += v0.w;
            a1[0] += v1.x; a1[1] += v1.y; a1[2] += v1.z; a1[3] += v1.w;
            a2[0] += v2.x; a2[1] += v2.y; a2[2] += v2.z; a2[3] += v2.w;
            a3[0] += v3.x; a3[1] += v3.y; a3[2] += v3.z; a3[3] += v3.w;
        }
        for (; j < e; j += MPI) {
            float4 v = *(const float4*)(sp + (size_t)idx[j] * C + cbase);
            a0[0] += v.x; a0[1] += v.y; a0[2] += v.z; a0[3] += v.w;
        }
    }

    float acc[CPL];
#pragma unroll
    for (int k = 0; k < CPL; ++k) acc[k] = (a0[k] + a1[k]) + (a2[k] + a3[k]);

#pragma unroll
    for (int st = LPR; st < 64; st <<= 1)
#pragma unroll
        for (int k = 0; k < CPL; ++k)
            acc[k] += __shfl_xor(acc[k], st);

    if (lane < LPR) {
        const float inv = 1.f / fmaxf((float)(e - b), 1.f);
#pragma unroll
        for (int k = 0; k < CPL; ++k) {
            float v = acc[k] * inv;
            if constexpr (DORELU) v = fmaxf(v, 0.f);
            if constexpr (EPI == 0) {
                (dstf + (size_t)sign * dstf_stride)[(size_t)s * C + cbase + k] = v;
            } else if constexpr (EPI == 1) {
                (dB + (size_t)sign * dB_stride)[(size_t)s * C + cbase + k] = f2bf_rne(v);
            } else if constexpr (EPI == 2) {
                ushort_t h = f2bf_rne(v);
                (dH + (size_t)sign * hl_stride)[(size_t)s * C + cbase + k] = h;
                (dL + (size_t)sign * hl_stride)[(size_t)s * C + cbase + k] = f2bf_rne(v - bf2f(h));
            } else {
                (dstf + (size_t)sign * dstf_stride)[(size_t)s * C + cbase + k] = v;
                (dB + (size_t)sign * dB_stride)[(size_t)s * C + cbase + k] = f2bf_rne(v);
            }
        }
    }
}

extern "C" void kernel_launch(void* const* d_in, const int* in_sizes, int n_in,
                              void* d_out, int out_size, void* d_ws, size_t ws_size,
                              hipStream_t stream)
{
    const float* m_emb = (const float*)d_in[0];
    const int*   v_pos = (const int*)d_in[1];
    const int*   e_pos = (const int*)d_in[2];
    const int*   v_neg = (const int*)d_in[3];
    const int*   e_neg = (const int*)d_in[4];
    const float* W0  = (const float*)d_in[5];
    const float* b0  = (const float*)d_in[6];
    const float* W1  = (const float*)d_in[7];
    const float* b1  = (const float*)d_in[8];
    const float* W2  = (const float*)d_in[9];
    const float* b2  = (const float*)d_in[10];
    const float* Wt1 = (const float*)d_in[11];
    const float* bt1 = (const float*)d_in[12];
    const float* Wt2 = (const float*)d_in[13];
    const float* bt2 = (const float*)d_in[14];
    float* out = (float*)d_out;

    // ---- workspace carve (~330 MB) ----
    char* p = (char*)d_ws;
    auto carve = [&](size_t bytes) { char* r = p; p += (bytes + 255) & ~(size_t)255; return r; };
    const size_t NA = (size_t)NNODES * 512;                // 25.6M elems
    char* regionA = carve(NA * 2 * 2);                     // 102.4 MB
    char* regionB = carve(NA * 2 * 2);                     // 102.4 MB
    ushort_t* Xt1b = (ushort_t*)carve((size_t)NNODES * 256 * 2);       // 25.6 MB
    ushort_t* Xt2b = (ushort_t*)carve((size_t)2 * NNODES * 128 * 2);   // 25.6 MB
    ushort_t* Y2b  = (ushort_t*)carve((size_t)2 * NEDGES * 128 * 2);   // 51.2 MB

    ushort_t* h0H = (ushort_t*)regionA; ushort_t* h0L = h0H + NA;
    ushort_t* h1H = (ushort_t*)regionB; ushort_t* h1L = h1H + NA;
    ushort_t* featH = h0H;  ushort_t* featL = h0L;          // G2 overwrites h0
    ushort_t* Y1b  = (ushort_t*)regionB;                    // [2][100000][256], h1 dead
    ushort_t* X1H  = (ushort_t*)regionA;                    // [2*50000][256], feat dead
    ushort_t* X1L  = X1H + (size_t)2 * NNODES * 256;

    ushort_t* W0tH  = (ushort_t*)carve((size_t)512 * 2816 * 2);
    ushort_t* W0tL  = (ushort_t*)carve((size_t)512 * 2816 * 2);
    ushort_t* W1tH  = (ushort_t*)carve((size_t)512 * 512 * 2);
    ushort_t* W1tL  = (ushort_t*)carve((size_t)512 * 512 * 2);
    ushort_t* W2tH  = (ushort_t*)carve((size_t)512 * 512 * 2);
    ushort_t* W2tL  = (ushort_t*)carve((size_t)512 * 512 * 2);
    ushort_t* Wt1tH = (ushort_t*)carve((size_t)256 * 512 * 2);
    ushort_t* Wt1tL = (ushort_t*)carve((size_t)256 * 512 * 2);
    ushort_t* Wt2tH = (ushort_t*)carve((size_t)128 * 256 * 2);
    ushort_t* Wt2tL = (ushort_t*)carve((size_t)128 * 256 * 2);
    int* e_off  = (int*)carve((size_t)2 * (NEDGES + 1) * 4);
    int* v_off  = (int*)carve((size_t)2 * (NNODES + 1) * 4);
    int* e_by_v = (int*)carve((size_t)2 * NP * 4);
    int* v_cnt  = (int*)carve((size_t)2 * NNODES * 4);

    const int MB = (NNODES + 127) / 128;       // 391
    const int MB2 = (2 * NNODES + 127) / 128;  // 782

    // ---- weight prep (one fused launch, 2080 blocks) ----
    prep_all<<<2080, 256, 0, stream>>>(W0, W1, W2, Wt1, Wt2,
        W0tH, W0tL, W1tH, W1tL, W2tH, W2tL, Wt1tH, Wt1tL, Wt2tH, Wt2tL);

    // ---- CSR for both signs ----
    hipMemsetAsync(v_cnt, 0, (size_t)2 * NNODES * 4, stream);
    build_csr1<<<dim3(1024, 2), 256, 0, stream>>>(e_pos, e_neg, v_pos, v_neg, e_off, v_cnt);
    exscan2<<<2, 1024, 0, stream>>>(v_cnt, v_off);
    scatter_both<<<dim3(1024, 2), 256, 0, stream>>>(v_pos, v_neg, e_pos, e_neg,
                                                    v_off, v_cnt, e_by_v);

    // ---- MLP ----
    gemm_bf3<true, true, 2><<<dim3(4, MB), 256, 0, stream>>>(
        m_emb, nullptr, nullptr, W0tH, W0tL, b0, nullptr, nullptr, h0H, h0L, NNODES, 512, 2816);
    gemm_bf3<false, true, 2><<<dim3(4, MB), 256, 0, stream>>>(
        nullptr, h0H, h0L, W1tH, W1tL, b1, nullptr, nullptr, h1H, h1L, NNODES, 512, 512);
    gemm_bf3<false, false, 2><<<dim3(4, MB), 256, 0, stream>>>(
        nullptr, h1H, h1L, W2tH, W2tL, b2, nullptr, nullptr, featH, featL, NNODES, 512, 512);

    // ---- layer-1 dense (shared by both signs) ----
    gemm_bf3<false, false, 1><<<dim3(2, MB), 256, 0, stream>>>(
        nullptr, featH, featL, Wt1tH, Wt1tL, bt1, nullptr, Xt1b, nullptr, nullptr, NNODES, 256, 512);

    // ---- layer-1 aggregation, both signs ----
    seg_mean2<true, 256, false, 1><<<dim3(NEDGES / 4, 2), 256, 0, stream>>>(
        Xt1b, 0, v_pos, v_neg, e_off, NEDGES + 1,
        nullptr, 0, Y1b, (long long)NEDGES * 256, nullptr, nullptr, 0, NEDGES);
    seg_mean2<true, 256, true, 2><<<dim3(NNODES / 4, 2), 256, 0, stream>>>(
        Y1b, (long long)NEDGES * 256, e_by_v, e_by_v + NP, v_off, NNODES + 1,
        nullptr, 0, nullptr, 0, X1H, X1L, (long long)NNODES * 256, NNODES);

    // ---- layer-2 dense: one GEMM over both signs (M = 100000) ----
    gemm_bf3<false, false, 1><<<dim3(1, MB2), 256, 0, stream>>>(
        nullptr, X1H, X1L, Wt2tH, Wt2tL, bt2, nullptr, Xt2b, nullptr, nullptr, 2 * NNODES, 128, 256);

    // ---- layer-2 aggregation, both signs ----
    // out layout: X1 @0, X2 @6.4M, Y_pos @12.8M, Y_neg @25.6M
    seg_mean2<true, 128, false, 3><<<dim3(NEDGES / 4, 2), 256, 0, stream>>>(
        Xt2b, (long long)NNODES * 128, v_pos, v_neg, e_off, NEDGES + 1,
        out + 12800000, 12800000LL, Y2b, (long long)NEDGES * 128, nullptr, nullptr, 0, NEDGES);
    seg_mean2<true, 128, false, 0><<<dim3(NNODES / 4, 2), 256, 0, stream>>>(
        Y2b, (long long)NEDGES * 128, e_by_v, e_by_v + NP, v_off, NNODES + 1,
        out, 6400000LL, nullptr, 0, nullptr, nullptr, 0, NNODES);
}

// Round 6
// 1955.078 us; speedup vs baseline: 3.3488x; 1.1032x over previous
//
#include <hip/hip_runtime.h>

#define NP 1600000
#define NNODES 50000
#define NEDGES 100000

typedef short bf16x8 __attribute__((ext_vector_type(8)));
typedef short short4b __attribute__((ext_vector_type(4)));
typedef float f32x4 __attribute__((ext_vector_type(4)));
typedef unsigned short ushort_t;

static __device__ __forceinline__ ushort_t f2bf_rne(float f) {
    __bf16 b = (__bf16)f;
    return __builtin_bit_cast(ushort_t, b);
}
static __device__ __forceinline__ float bf2f(ushort_t h) {
    union { float f; unsigned int u; } v; v.u = ((unsigned int)h) << 16;
    return v.f;
}
static __device__ __forceinline__ void addbf8(float* a, uint4 u) {
    unsigned int uu[4] = {u.x, u.y, u.z, u.w};
#pragma unroll
    for (int q = 0; q < 4; ++q) {
        union { float f; unsigned int v; } lo, hi;
        lo.v = uu[q] << 16; hi.v = uu[q] & 0xffff0000u;
        a[2 * q]     += lo.f;
        a[2 * q + 1] += hi.f;
    }
}

static __device__ __forceinline__ void gload_lds16(const void* g, void* lds) {
    __builtin_amdgcn_global_load_lds(
        (const __attribute__((address_space(1))) unsigned int*)g,
        (__attribute__((address_space(3))) unsigned int*)lds, 16, 0, 0);
}

// ---------------- split-2 MFMA GEMM -----------------------------------------
// C = A @ B + bias.  A [M,K] f32 (converted in-kernel) or bf16 single.
// B transposed [N,K] bf16 hi/lo.  C ~= Ah*Bh + Ah*Bl  (drops |Al*B| ~ 2^-9 rel).
// BM=BN=128, BK=32, 4 waves x (64x64), 16x16x32 MFMA.
// XCD-chunked bijective block swizzle (T1/m204).
// EPI: 0 = f32 out, 1 = bf16 out.
template<bool AF32, bool DORELU, int EPI>
__global__ __launch_bounds__(256, 3) void gemm_bf2(
    const float* __restrict__ Af, const ushort_t* __restrict__ Ab,
    const ushort_t* __restrict__ Bth, const ushort_t* __restrict__ Btl,
    const float* __restrict__ bias,
    float* __restrict__ Cf, ushort_t* __restrict__ Cb,
    int M, int N, int K)
{
    __shared__ ushort_t AsH[4][129][8];
    __shared__ ushort_t BsH[4][129][8];
    __shared__ ushort_t BsL[4][129][8];

    const int tid = threadIdx.x;
    const int wid = tid >> 6;
    const int lane = tid & 63;

    // bijective XCD-chunked swizzle
    const int nwg = gridDim.x * gridDim.y;
    const int wg  = blockIdx.y * gridDim.x + blockIdx.x;
    const int q = nwg >> 3, r = nwg & 7;
    const int xcd = wg & 7, loc = wg >> 3;
    const int swz = (xcd < r) ? (xcd * (q + 1) + loc)
                              : (r * (q + 1) + (xcd - r) * q + loc);
    const int bn0 = (int)(swz % gridDim.x) * 128;
    const int bm0 = (int)(swz / gridDim.x) * 128;

    const int wrow0 = (wid >> 1) * 64;
    const int wcol0 = (wid & 1) * 64;

    f32x4 acc[4][4];
#pragma unroll
    for (int i = 0; i < 4; ++i)
#pragma unroll
        for (int j = 0; j < 4; ++j) acc[i][j] = (f32x4)0.f;

    const int nk = K >> 5;
    const int kgl = lane >> 4;
    const int r16 = lane & 15;

    // AF32 A-staging geometry (register prefetch pipeline)
    const int a_kq   = tid & 7;
    const int a_row0 = tid >> 3;
    const float* aBase[4];
    float4 aPre[4];
    if constexpr (AF32) {
#pragma unroll
        for (int cch = 0; cch < 4; ++cch) {
            int row = cch * 32 + a_row0;
            int rr = bm0 + row; if (rr > M - 1) rr = M - 1;
            aBase[cch] = Af + (size_t)rr * K + a_kq * 4;
            aPre[cch] = *(const float4*)(aBase[cch]);
        }
    }

    for (int kt = 0; kt < nk; ++kt) {
        __syncthreads();
        // ---- stage B (async direct-to-LDS, hi+lo) ----
#pragma unroll
        for (int h = 0; h < 2; ++h) {
            int c = bn0 + h * 64 + lane;
            const ushort_t* gbh = Bth + (size_t)c * K + kt * 32 + wid * 8;
            const ushort_t* gbl = Btl + (size_t)c * K + kt * 32 + wid * 8;
            gload_lds16(gbh, &BsH[wid][h * 64][0]);
            gload_lds16(gbl, &BsL[wid][h * 64][0]);
        }
        // ---- stage A (single bf16 plane) ----
        if constexpr (AF32) {
#pragma unroll
            for (int cch = 0; cch < 4; ++cch) {
                int row = cch * 32 + a_row0;
                float4 v = aPre[cch];
                short4b hi;
                hi[0] = (short)f2bf_rne(v.x); hi[1] = (short)f2bf_rne(v.y);
                hi[2] = (short)f2bf_rne(v.z); hi[3] = (short)f2bf_rne(v.w);
                int kg = a_kq >> 1, j0 = (a_kq & 1) * 4;
                *(short4b*)&AsH[kg][row][j0] = hi;
            }
        } else {
#pragma unroll
            for (int h = 0; h < 2; ++h) {
                int rr = bm0 + h * 64 + lane; if (rr > M - 1) rr = M - 1;
                gload_lds16(Ab + (size_t)rr * K + kt * 32 + wid * 8,
                            &AsH[wid][h * 64][0]);
            }
        }
        __syncthreads();

        // issue next A f32 loads; latency hides under MFMA
        if constexpr (AF32) {
            if (kt + 1 < nk) {
#pragma unroll
                for (int cch = 0; cch < 4; ++cch)
                    aPre[cch] = *(const float4*)(aBase[cch] + (kt + 1) * 32);
            }
        }

        bf16x8 ah[4], bh[4], bl[4];
#pragma unroll
        for (int mi = 0; mi < 4; ++mi)
            ah[mi] = *(const bf16x8*)&AsH[kgl][wrow0 + mi * 16 + r16][0];
#pragma unroll
        for (int ni = 0; ni < 4; ++ni) {
            bh[ni] = *(const bf16x8*)&BsH[kgl][wcol0 + ni * 16 + r16][0];
            bl[ni] = *(const bf16x8*)&BsL[kgl][wcol0 + ni * 16 + r16][0];
        }
#pragma unroll
        for (int mi = 0; mi < 4; ++mi)
#pragma unroll
            for (int ni = 0; ni < 4; ++ni) {
                acc[mi][ni] = __builtin_amdgcn_mfma_f32_16x16x32_bf16(ah[mi], bh[ni], acc[mi][ni], 0, 0, 0);
                acc[mi][ni] = __builtin_amdgcn_mfma_f32_16x16x32_bf16(ah[mi], bl[ni], acc[mi][ni], 0, 0, 0);
            }
    }

    // ---- epilogue: C/D layout col=lane&15 (N), row=(lane>>4)*4+reg (M) ----
    const int rg4 = (lane >> 4) * 4;
#pragma unroll
    for (int ni = 0; ni < 4; ++ni) {
        int gcol = bn0 + wcol0 + ni * 16 + r16;
        float bb = bias[gcol];
#pragma unroll
        for (int mi = 0; mi < 4; ++mi)
#pragma unroll
            for (int rg = 0; rg < 4; ++rg) {
                int grow = bm0 + wrow0 + mi * 16 + rg4 + rg;
                if (grow < M) {
                    float v = acc[mi][ni][rg] + bb;
                    if constexpr (DORELU) v = fmaxf(v, 0.f);
                    if constexpr (EPI == 0) Cf[(size_t)grow * N + gcol] = v;
                    else                    Cb[(size_t)grow * N + gcol] = f2bf_rne(v);
                }
            }
    }
}

// ---------------- fused: weight transpose/split + CSR pass 1 ----------------
// blocks [0,2080): weight prep; blocks [2080, 2080+2048): edge offsets + v hist
__global__ __launch_bounds__(256) void prep_and_csr(
    const float* __restrict__ W0, const float* __restrict__ W1,
    const float* __restrict__ W2, const float* __restrict__ Wt1,
    const float* __restrict__ Wt2,
    ushort_t* __restrict__ W0tH, ushort_t* __restrict__ W0tL,
    ushort_t* __restrict__ W1tH, ushort_t* __restrict__ W1tL,
    ushort_t* __restrict__ W2tH, ushort_t* __restrict__ W2tL,
    ushort_t* __restrict__ Wt1tH, ushort_t* __restrict__ Wt1tL,
    ushort_t* __restrict__ Wt2tH, ushort_t* __restrict__ Wt2tL,
    const int* __restrict__ ePos, const int* __restrict__ eNeg,
    const int* __restrict__ vPos, const int* __restrict__ vNeg,
    int* __restrict__ e_off, int* __restrict__ v_cnt)
{
    const int bsel = blockIdx.x;
    if (bsel >= 2080) {
        const int rel = bsel - 2080;
        const int sign = rel >> 10;                 // 1024 blocks per sign
        const int* e_idx = sign ? eNeg : ePos;
        const int* v_idx = sign ? vNeg : vPos;
        int* o  = e_off + sign * (NEDGES + 1);
        int* vc = v_cnt + sign * NNODES;
        int i = (rel & 1023) * 256 + threadIdx.x;
        const int stride = 1024 * 256;
        for (; i < NP; i += stride) {
            int cur = e_idx[i];
            int prev = (i > 0) ? e_idx[i - 1] : -1;
            for (int e = prev + 1; e <= cur; ++e) o[e] = i;
            if (i == NP - 1)
                for (int e = cur + 1; e <= NEDGES; ++e) o[e] = NP;
            atomicAdd(&vc[v_idx[i]], 1);
        }
        return;
    }
    const float* W; ushort_t* H; ushort_t* L; int K, N, nx, rel;
    if (bsel < 1408)      { W = W0;  H = W0tH;  L = W0tL;  K = 2816; N = 512; nx = 16; rel = bsel; }
    else if (bsel < 1664) { W = W1;  H = W1tH;  L = W1tL;  K = 512;  N = 512; nx = 16; rel = bsel - 1408; }
    else if (bsel < 1920) { W = W2;  H = W2tH;  L = W2tL;  K = 512;  N = 512; nx = 16; rel = bsel - 1664; }
    else if (bsel < 2048) { W = Wt1; H = Wt1tH; L = Wt1tL; K = 512;  N = 256; nx = 8;  rel = bsel - 1920; }
    else                  { W = Wt2; H = Wt2tH; L = Wt2tL; K = 256;  N = 128; nx = 4;  rel = bsel - 2048; }
    const int n0 = (rel % nx) * 32, k0 = (rel / nx) * 32;

    __shared__ float T[32][33];
    const int c = threadIdx.x & 31, r8 = threadIdx.x >> 5;
#pragma unroll
    for (int i = 0; i < 4; ++i)
        T[r8 + i * 8][c] = W[(size_t)(k0 + r8 + i * 8) * N + n0 + c];
    __syncthreads();
#pragma unroll
    for (int i = 0; i < 4; ++i) {
        int nr = r8 + i * 8;
        float v = T[c][nr];
        ushort_t h = f2bf_rne(v);
        H[(size_t)(n0 + nr) * K + k0 + c] = h;
        L[(size_t)(n0 + nr) * K + k0 + c] = f2bf_rne(v - bf2f(h));
    }
}

__global__ __launch_bounds__(1024) void exscan2(const int* __restrict__ cnt,
                                                int* __restrict__ off)
{
    const int sign = blockIdx.x;
    const int* c = cnt + sign * NNODES;
    int* o = off + sign * (NNODES + 1);
    __shared__ int sums[1024];
    const int t = threadIdx.x;
    const int per = (NNODES + 1023) >> 10;
    const int b = t * per;
    const int e = min(b + per, NNODES);
    int s = 0;
    for (int i = b; i < e; ++i) s += c[i];
    sums[t] = s;
    __syncthreads();
    for (int d = 1; d < 1024; d <<= 1) {
        int v = (t >= d) ? sums[t - d] : 0;
        __syncthreads();
        sums[t] += v;
        __syncthreads();
    }
    int run = (t > 0) ? sums[t - 1] : 0;
    for (int i = b; i < e; ++i) { o[i] = run; run += c[i]; }
    if (t == 1023) o[NNODES] = run;
}

__global__ void scatter_both(const int* __restrict__ vPos, const int* __restrict__ vNeg,
                             const int* __restrict__ ePos, const int* __restrict__ eNeg,
                             const int* __restrict__ v_off, int* __restrict__ v_cnt,
                             int* __restrict__ e_by_v)
{
    const int sign = blockIdx.y;
    const int* v_idx = sign ? vNeg : vPos;
    const int* e_idx = sign ? eNeg : ePos;
    const int* vo = v_off + sign * (NNODES + 1);
    int* vc = v_cnt + sign * NNODES;
    int* ebv = e_by_v + sign * NP;
    int i = blockIdx.x * blockDim.x + threadIdx.x;
    int stride = gridDim.x * blockDim.x;
    for (; i < NP; i += stride) {
        int v = v_idx[i];
        int pos = atomicSub(&vc[v], 1) - 1;
        ebv[vo[v] + pos] = e_idx[i];
    }
}

// ---------------- segment mean, dual-sign, 16B/lane, 4-wide gather ----------
// EPI: 0 f32 out, 1 bf16 out, 3 f32 out + bf16 shadow.
template<bool SRCBF, int C, bool DORELU, int EPI>
__global__ __launch_bounds__(256) void seg_mean2(
    const void* __restrict__ src, long long src_stride,
    const int* __restrict__ idx0, const int* __restrict__ idx1,
    const int* __restrict__ off_base, int off_stride,
    float* __restrict__ dstf, long long dstf_stride,
    ushort_t* __restrict__ dB, long long dB_stride,
    int nseg)
{
    constexpr int ES  = SRCBF ? 2 : 4;
    constexpr int LPR = (C * ES) / 16;    // lanes covering one row
    constexpr int MPI = 64 / LPR;         // members per wave-iteration
    constexpr int CPL = 16 / ES;          // channels per lane

    const int sign = blockIdx.y;
    const int* idx = sign ? idx1 : idx0;
    const int* off = off_base + (size_t)sign * off_stride;

    const int wave = threadIdx.x >> 6, lane = threadIdx.x & 63;
    const int s = blockIdx.x * 4 + wave;
    if (s >= nseg) return;
    const int b = off[s], e = off[s + 1];
    const int sub = lane / LPR;
    const int cbase = (lane % LPR) * CPL;

    float a0[CPL], a1[CPL], a2[CPL], a3[CPL];
#pragma unroll
    for (int k = 0; k < CPL; ++k) { a0[k] = 0.f; a1[k] = 0.f; a2[k] = 0.f; a3[k] = 0.f; }

    int j = b + sub;
    if constexpr (SRCBF) {
        const ushort_t* sp = (const ushort_t*)src + (size_t)sign * src_stride;
        for (; j + 3 * MPI < e; j += 4 * MPI) {
            int i0 = idx[j], i1 = idx[j + MPI], i2 = idx[j + 2 * MPI], i3 = idx[j + 3 * MPI];
            uint4 u0 = *(const uint4*)(sp + (size_t)i0 * C + cbase);
            uint4 u1 = *(const uint4*)(sp + (size_t)i1 * C + cbase);
            uint4 u2 = *(const uint4*)(sp + (size_t)i2 * C + cbase);
            uint4 u3 = *(const uint4*)(sp + (size_t)i3 * C + cbase);
            addbf8(a0, u0); addbf8(a1, u1); addbf8(a2, u2); addbf8(a3, u3);
        }
        for (; j < e; j += MPI) {
            uint4 u = *(const uint4*)(sp + (size_t)idx[j] * C + cbase);
            addbf8(a0, u);
        }
    } else {
        const float* sp = (const float*)src + (size_t)sign * src_stride;
        for (; j + 3 * MPI < e; j += 4 * MPI) {
            int i0 = idx[j], i1 = idx[j + MPI], i2 = idx[j + 2 * MPI], i3 = idx[j + 3 * MPI];
            float4 v0 = *(const float4*)(sp + (size_t)i0 * C + cbase);
            float4 v1 = *(const float4*)(sp + (size_t)i1 * C + cbase);
            float4 v2 = *(const float4*)(sp + (size_t)i2 * C + cbase);
            float4 v3 = *(const float4*)(sp + (size_t)i3 * C + cbase);
            a0[0] += v0.x; a0[1] += v0.y; a0[2] += v0.z; a0[3] += v0.w;
            a1[0] += v1.x; a1[1] += v1.y; a1[2] += v1.z; a1[3] += v1.w;
            a2[0] += v2.x; a2[1] += v2.y; a2[2] += v2.z; a2[3] += v2.w;
            a3[0] += v3.x; a3[1] += v3.y; a3[2] += v3.z; a3[3] += v3.w;
        }
        for (; j < e; j += MPI) {
            float4 v = *(const float4*)(sp + (size_t)idx[j] * C + cbase);
            a0[0] += v.x; a0[1] += v.y; a0[2] += v.z; a0[3] += v.w;
        }
    }

    float acc[CPL];
#pragma unroll
    for (int k = 0; k < CPL; ++k) acc[k] = (a0[k] + a1[k]) + (a2[k] + a3[k]);

#pragma unroll
    for (int st = LPR; st < 64; st <<= 1)
#pragma unroll
        for (int k = 0; k < CPL; ++k)
            acc[k] += __shfl_xor(acc[k], st);

    if (lane < LPR) {
        const float inv = 1.f / fmaxf((float)(e - b), 1.f);
#pragma unroll
        for (int k = 0; k < CPL; ++k) {
            float v = acc[k] * inv;
            if constexpr (DORELU) v = fmaxf(v, 0.f);
            if constexpr (EPI == 0) {
                (dstf + (size_t)sign * dstf_stride)[(size_t)s * C + cbase + k] = v;
            } else if constexpr (EPI == 1) {
                (dB + (size_t)sign * dB_stride)[(size_t)s * C + cbase + k] = f2bf_rne(v);
            } else {
                (dstf + (size_t)sign * dstf_stride)[(size_t)s * C + cbase + k] = v;
                (dB + (size_t)sign * dB_stride)[(size_t)s * C + cbase + k] = f2bf_rne(v);
            }
        }
    }
}

extern "C" void kernel_launch(void* const* d_in, const int* in_sizes, int n_in,
                              void* d_out, int out_size, void* d_ws, size_t ws_size,
                              hipStream_t stream)
{
    const float* m_emb = (const float*)d_in[0];
    const int*   v_pos = (const int*)d_in[1];
    const int*   e_pos = (const int*)d_in[2];
    const int*   v_neg = (const int*)d_in[3];
    const int*   e_neg = (const int*)d_in[4];
    const float* W0  = (const float*)d_in[5];
    const float* b0  = (const float*)d_in[6];
    const float* W1  = (const float*)d_in[7];
    const float* b1  = (const float*)d_in[8];
    const float* W2  = (const float*)d_in[9];
    const float* b2  = (const float*)d_in[10];
    const float* Wt1 = (const float*)d_in[11];
    const float* bt1 = (const float*)d_in[12];
    const float* Wt2 = (const float*)d_in[13];
    const float* bt2 = (const float*)d_in[14];
    float* out = (float*)d_out;

    // ---- workspace carve ----
    char* p = (char*)d_ws;
    auto carve = [&](size_t bytes) { char* r = p; p += (bytes + 255) & ~(size_t)255; return r; };
    const size_t NA = (size_t)NNODES * 512;                          // 25.6M elems
    ushort_t* regionA = (ushort_t*)carve(NA * 2);                    // 51.2 MB: h0b -> featb
    ushort_t* regionB = (ushort_t*)carve(NA * 2);                    // 51.2 MB: h1b -> X1b
    ushort_t* Y1b  = (ushort_t*)carve((size_t)2 * NEDGES * 256 * 2); // 102.4 MB
    ushort_t* Xt1b = (ushort_t*)carve((size_t)NNODES * 256 * 2);     // 25.6 MB
    ushort_t* Xt2b = (ushort_t*)carve((size_t)2 * NNODES * 128 * 2); // 25.6 MB
    ushort_t* Y2b  = (ushort_t*)carve((size_t)2 * NEDGES * 128 * 2); // 51.2 MB

    ushort_t* h0b = regionA;
    ushort_t* h1b = regionB;
    ushort_t* featb = regionA;               // G2 output overwrites h0
    ushort_t* X1b = regionB;                 // [2*50000][256]; h1 dead after G2

    ushort_t* W0tH  = (ushort_t*)carve((size_t)512 * 2816 * 2);
    ushort_t* W0tL  = (ushort_t*)carve((size_t)512 * 2816 * 2);
    ushort_t* W1tH  = (ushort_t*)carve((size_t)512 * 512 * 2);
    ushort_t* W1tL  = (ushort_t*)carve((size_t)512 * 512 * 2);
    ushort_t* W2tH  = (ushort_t*)carve((size_t)512 * 512 * 2);
    ushort_t* W2tL  = (ushort_t*)carve((size_t)512 * 512 * 2);
    ushort_t* Wt1tH = (ushort_t*)carve((size_t)256 * 512 * 2);
    ushort_t* Wt1tL = (ushort_t*)carve((size_t)256 * 512 * 2);
    ushort_t* Wt2tH = (ushort_t*)carve((size_t)128 * 256 * 2);
    ushort_t* Wt2tL = (ushort_t*)carve((size_t)128 * 256 * 2);
    int* e_off  = (int*)carve((size_t)2 * (NEDGES + 1) * 4);
    int* v_off  = (int*)carve((size_t)2 * (NNODES + 1) * 4);
    int* e_by_v = (int*)carve((size_t)2 * NP * 4);
    int* v_cnt  = (int*)carve((size_t)2 * NNODES * 4);

    const int MB = (NNODES + 127) / 128;       // 391
    const int MB2 = (2 * NNODES + 127) / 128;  // 782

    // ---- fused weight prep + CSR pass 1 ----
    hipMemsetAsync(v_cnt, 0, (size_t)2 * NNODES * 4, stream);
    prep_and_csr<<<2080 + 2048, 256, 0, stream>>>(
        W0, W1, W2, Wt1, Wt2,
        W0tH, W0tL, W1tH, W1tL, W2tH, W2tL, Wt1tH, Wt1tL, Wt2tH, Wt2tL,
        e_pos, e_neg, v_pos, v_neg, e_off, v_cnt);
    exscan2<<<2, 1024, 0, stream>>>(v_cnt, v_off);
    scatter_both<<<dim3(1024, 2), 256, 0, stream>>>(v_pos, v_neg, e_pos, e_neg,
                                                    v_off, v_cnt, e_by_v);

    // ---- MLP ----
    gemm_bf2<true, true, 1><<<dim3(4, MB), 256, 0, stream>>>(
        m_emb, nullptr, W0tH, W0tL, b0, nullptr, h0b, NNODES, 512, 2816);
    gemm_bf2<false, true, 1><<<dim3(4, MB), 256, 0, stream>>>(
        nullptr, h0b, W1tH, W1tL, b1, nullptr, h1b, NNODES, 512, 512);
    gemm_bf2<false, false, 1><<<dim3(4, MB), 256, 0, stream>>>(
        nullptr, h1b, W2tH, W2tL, b2, nullptr, featb, NNODES, 512, 512);

    // ---- layer-1 dense (shared by both signs) ----
    gemm_bf2<false, false, 1><<<dim3(2, MB), 256, 0, stream>>>(
        nullptr, featb, Wt1tH, Wt1tL, bt1, nullptr, Xt1b, NNODES, 256, 512);

    // ---- layer-1 aggregation, both signs ----
    seg_mean2<true, 256, false, 1><<<dim3(NEDGES / 4, 2), 256, 0, stream>>>(
        Xt1b, 0, v_pos, v_neg, e_off, NEDGES + 1,
        nullptr, 0, Y1b, (long long)NEDGES * 256, NEDGES);
    seg_mean2<true, 256, true, 1><<<dim3(NNODES / 4, 2), 256, 0, stream>>>(
        Y1b, (long long)NEDGES * 256, e_by_v, e_by_v + NP, v_off, NNODES + 1,
        nullptr, 0, X1b, (long long)NNODES * 256, NNODES);

    // ---- layer-2 dense: one GEMM over both signs (M = 100000) ----
    gemm_bf2<false, false, 1><<<dim3(1, MB2), 256, 0, stream>>>(
        nullptr, X1b, Wt2tH, Wt2tL, bt2, nullptr, Xt2b, 2 * NNODES, 128, 256);

    // ---- layer-2 aggregation, both signs ----
    // out layout: X1 @0, X2 @6.4M, Y_pos @12.8M, Y_neg @25.6M
    seg_mean2<true, 128, false, 3><<<dim3(NEDGES / 4, 2), 256, 0, stream>>>(
        Xt2b, (long long)NNODES * 128, v_pos, v_neg, e_off, NEDGES + 1,
        out + 12800000, 12800000LL, Y2b, (long long)NEDGES * 128, NEDGES);
    seg_mean2<true, 128, false, 0><<<dim3(NNODES / 4, 2), 256, 0, stream>>>(
        Y2b, (long long)NEDGES * 128, e_by_v, e_by_v + NP, v_off, NNODES + 1,
        out, 6400000LL, nullptr, 0, NNODES);
}